// Round 13
// baseline (277.570 us; speedup 1.0000x reference)
//
#include <hip/hip_runtime.h>
#include <hip/hip_bf16.h>

// Problem constants
constexpr int Bn = 4, Sn = 2048, Dn = 1024, Hn = 16, DKn = 64;
constexpr int Mrows = Bn * Sn;  // 8192
constexpr int NQB = Sn / 64;    // 32 q-chunks of 64 rows

typedef __attribute__((ext_vector_type(8))) short short8;
typedef __attribute__((ext_vector_type(4))) float f32x4;
typedef __attribute__((ext_vector_type(4))) unsigned int u32x4;

#define DEV __device__ __forceinline__

// fp32 -> bf16 RNE, scalar (epilogue scatter only)
DEV unsigned short f2bf(float f) {
    unsigned u = __builtin_bit_cast(unsigned, f);
    u += 0x7FFFu + ((u >> 16) & 1u);
    return (unsigned short)(u >> 16);
}
// fp32 pair -> packed bf16x2 via v_cvt_pk_bf16_f32 (hardware RNE)
DEV unsigned pk2(float a, float b) {
    __hip_bfloat162 h = __float22bfloat162_rn(float2{a, b});
    unsigned u;
    __builtin_memcpy(&u, &h, 4);
    return u;
}
// 2^x via v_exp_f32
DEV float exp2a(float x) {
    float r;
    asm("v_exp_f32 %0, %1" : "=v"(r) : "v"(x));
    return r;
}

// ---------------------------------------------------------------------------
// Weights fp32 -> bf16, one matrix per blockIdx.y. 8 elems/thread.
// ---------------------------------------------------------------------------
__global__ __launch_bounds__(256) void cvt_w(const float* __restrict__ W0,
                                             const float* __restrict__ W1,
                                             const float* __restrict__ W2,
                                             const float* __restrict__ W3,
                                             unsigned short* __restrict__ Out) {
    const float* src = blockIdx.y == 0 ? W0
                     : blockIdx.y == 1 ? W1
                     : blockIdx.y == 2 ? W2 : W3;
    size_t off = ((size_t)blockIdx.x * 256 + threadIdx.x) * 8;
    const float4* s = (const float4*)(src + off);
    float4 a = s[0], b = s[1];
    u32x4 p = {pk2(a.x, a.y), pk2(a.z, a.w), pk2(b.x, b.y), pk2(b.z, b.w)};
    *(u32x4*)(Out + (size_t)blockIdx.y * (Dn * Dn) + off) = p;
}

// ---------------------------------------------------------------------------
// GEMM body: C[m,n] = sum_k A[m,k] * W[n,k]  (y = x @ W^T), M=8192, N=K=1024.
// 128x128 tile, BK=32, 256 threads (4 waves, 2x2 wave grid, 64x64 per wave).
// XCD-AWARE REMAP (R12 win): all 8 n-blocks of one A-panel share bid%8 ->
// same XCD L2; per-XCD A set = 4MB = L2 size. Bijective.
// Reg-prefetch of next K-step during compute. A/B optionally bf16.
// ---------------------------------------------------------------------------
template <bool ABF16, bool BBF16, bool OUTF32>
DEV void gemm_body(const void* __restrict__ Ap, const void* __restrict__ Bw,
                   void* __restrict__ Out) {
    __shared__ alignas(16) unsigned short As[128 * 40];
    __shared__ alignas(16) unsigned short Bs[128 * 40];

    const int tid = threadIdx.x;
    const int bid = (int)(blockIdx.y * gridDim.x + blockIdx.x);
    const int xcd = bid & 7;
    const int jj = bid >> 3;
    const int m0 = (xcd + ((jj & 7) << 3)) * 128;  // 64 m-panels
    const int n0 = (jj >> 3) * 128;                // 8 n-panels
    const int lane = tid & 63;
    const int w = tid >> 6;
    const int wm = (w >> 1) * 64, wn = (w & 1) * 64;
    const int g = lane >> 4, q15 = lane & 15;

    f32x4 acc[4][4] = {};

    const int srow = tid >> 1, shalf = tid & 1;

    const float* Af = (const float*)Ap;
    const unsigned short* Ab = (const unsigned short*)Ap;
    const float* Bf = (const float*)Bw;
    const unsigned short* Bb = (const unsigned short*)Bw;

    float4 fa0, fa1, fa2, fa3, fb0, fb1, fb2, fb3;
    u32x4 ua0, ua1, ub0, ub1;

    auto loadA = [&](int kk) {
        if constexpr (ABF16) {
            const u32x4* s =
                (const u32x4*)(Ab + (size_t)(m0 + srow) * Dn + kk + shalf * 16);
            ua0 = s[0];
            ua1 = s[1];
        } else {
            const float4* s =
                (const float4*)(Af + (size_t)(m0 + srow) * Dn + kk + shalf * 16);
            fa0 = s[0]; fa1 = s[1]; fa2 = s[2]; fa3 = s[3];
        }
    };
    auto loadB = [&](int kk) {
        if constexpr (BBF16) {
            const u32x4* s =
                (const u32x4*)(Bb + (size_t)(n0 + srow) * Dn + kk + shalf * 16);
            ub0 = s[0];
            ub1 = s[1];
        } else {
            const float4* s =
                (const float4*)(Bf + (size_t)(n0 + srow) * Dn + kk + shalf * 16);
            fb0 = s[0]; fb1 = s[1]; fb2 = s[2]; fb3 = s[3];
        }
    };
    auto store = [&]() {
        u32x4* da = (u32x4*)(&As[srow * 40 + shalf * 16]);
        if constexpr (ABF16) {
            da[0] = ua0;
            da[1] = ua1;
        } else {
            u32x4 p0 = {pk2(fa0.x, fa0.y), pk2(fa0.z, fa0.w), pk2(fa1.x, fa1.y),
                        pk2(fa1.z, fa1.w)};
            u32x4 p1 = {pk2(fa2.x, fa2.y), pk2(fa2.z, fa2.w), pk2(fa3.x, fa3.y),
                        pk2(fa3.z, fa3.w)};
            da[0] = p0;
            da[1] = p1;
        }
        u32x4* db = (u32x4*)(&Bs[srow * 40 + shalf * 16]);
        if constexpr (BBF16) {
            db[0] = ub0;
            db[1] = ub1;
        } else {
            u32x4 q0 = {pk2(fb0.x, fb0.y), pk2(fb0.z, fb0.w), pk2(fb1.x, fb1.y),
                        pk2(fb1.z, fb1.w)};
            u32x4 q1 = {pk2(fb2.x, fb2.y), pk2(fb2.z, fb2.w), pk2(fb3.x, fb3.y),
                        pk2(fb3.z, fb3.w)};
            db[0] = q0;
            db[1] = q1;
        }
    };

    loadA(0);
    loadB(0);
    for (int kk = 0; kk < Dn; kk += 32) {
        store();
        __syncthreads();
        if (kk + 32 < Dn) {
            loadA(kk + 32);
            loadB(kk + 32);
        }

        short8 af[4], bf[4];
#pragma unroll
        for (int mf = 0; mf < 4; ++mf)
            af[mf] = __builtin_bit_cast(
                short8, *(const u32x4*)(&As[(wm + mf * 16 + q15) * 40 + g * 8]));
#pragma unroll
        for (int nf = 0; nf < 4; ++nf)
            bf[nf] = __builtin_bit_cast(
                short8, *(const u32x4*)(&Bs[(wn + nf * 16 + q15) * 40 + g * 8]));
#pragma unroll
        for (int mf = 0; mf < 4; ++mf)
#pragma unroll
            for (int nf = 0; nf < 4; ++nf)
                acc[mf][nf] = __builtin_amdgcn_mfma_f32_16x16x32_bf16(
                    af[mf], bf[nf], acc[mf][nf], 0, 0, 0);
        __syncthreads();
    }

#pragma unroll
    for (int mf = 0; mf < 4; ++mf)
#pragma unroll
        for (int nf = 0; nf < 4; ++nf)
#pragma unroll
            for (int r = 0; r < 4; ++r) {
                int m = m0 + wm + mf * 16 + 4 * g + r;
                int n = n0 + wn + nf * 16 + q15;
                float val = acc[mf][nf][r];
                if (OUTF32) {
                    ((float*)Out)[(size_t)m * Dn + n] = val;
                } else {
                    int b = m >> 11, s = m & (Sn - 1);
                    int h = n >> 6, dk = n & 63;
                    ((unsigned short*)Out)[(((size_t)(b * Hn + h) * Sn + s) << 6) +
                                           dk] = f2bf(val);
                }
            }
}

template <bool ABF16, bool BBF16, bool OUTF32>
__global__ __launch_bounds__(256) void gemm_nt(const void* __restrict__ Ap,
                                               const void* __restrict__ Bw,
                                               void* __restrict__ Out) {
    gemm_body<ABF16, BBF16, OUTF32>(Ap, Bw, Out);
}

// ---------------------------------------------------------------------------
// Causal flash attention, UNPAIRED: one 64-row q-chunk per block, grid
// (NQB, B*H) = 2048 blocks (~6 blocks/CU vs paired 4 — R12: occupancy was
// the limiter at 23.7%). qblk chosen so (a) per-XCD total work is equal
// (bid%8 = XCD since 32 | y-stride): XCD c gets lengths {32-c,17+c,16-c,
// 1+c} summing 66 for every c; (b) long blocks dispatch first (LPT).
// 256 threads = 4 waves, 16 q rows/wave. Single-buffer LDS:
//   Kt: [64kv][64dk] XOR-swizzled (byte ^= (row&7)<<4)
//   Vt: [64dk][64 kv-PERMUTED] transposed at staging (R11 win): col_new(kv)
//   = (kv&32)|((kv&12)<<1)|((kv&16)>>2)|(kv&3) makes the PV B-fragment the
//   lane's own packed pkk regs (no P-gather shuffles); bit0 preserved.
// QK^T swapped (sacc rows=kv, cols=q). Softmax: max over RAW scores (scale
// >0 commutes with max), scale folded into exp via FMA — saves 16 muls/iter.
// T13 defer-max; T14 reg-prefetch of next KV tile; T5 setprio around MFMA.
// NOTE: no min-waves in launch_bounds (R7: register cap -> 456MB spill).
// ---------------------------------------------------------------------------
__global__ __launch_bounds__(256) void attn_fwd(
    const unsigned short* __restrict__ Qb, const unsigned short* __restrict__ Kb,
    const unsigned short* __restrict__ Vb, unsigned short* __restrict__ Xb) {
    __shared__ alignas(16) unsigned short Kt[64 * 64];
    __shared__ alignas(16) unsigned short Vt[64 * 64];

    constexpr float SCL = 0.18033688f;  // 0.125 * log2(e)

    const int tid = threadIdx.x;
    const int xb = blockIdx.x;  // 0..31
    const int c = xb & 7, t = xb >> 3;
    const int qblk = t == 0 ? (31 - c) : t == 1 ? (16 + c) : t == 2 ? (15 - c) : c;
    const int bh = blockIdx.y;
    const int b = bh >> 4, h = bh & 15;
    const int lane = tid & 63, w = tid >> 6;
    const int g = lane >> 4, q15 = lane & 15;

    const unsigned short* Qh = Qb + (size_t)bh * Sn * DKn;
    const unsigned short* Kh = Kb + (size_t)bh * Sn * DKn;
    const unsigned short* Vh = Vb + (size_t)bh * Sn * DKn;

    const int st_row = tid >> 2, st_seg = tid & 3;  // K staging
    const int sv_kv = tid & 63, sv_g = tid >> 6;    // V staging
    const int sel = sv_kv & 1;
    // permuted byte col base in Vt (bit0 of kv preserved by col_new)
    const int kv_even = sv_kv & ~1;
    const unsigned kvp = (unsigned)(((kv_even & 32) | ((kv_even & 12) << 1) |
                                     ((kv_even & 16) >> 2) | (kv_even & 3)) *
                                    2);

    u32x4 kr0, kr1, vr0, vr1;  // prefetch registers
    auto load_kv = [&](int j) {
        kr0 = *(const u32x4*)(Kh + (size_t)(j * 64 + st_row) * DKn + st_seg * 8);
        kr1 = *(const u32x4*)(Kh + (size_t)(j * 64 + st_row) * DKn +
                              (st_seg + 4) * 8);
        vr0 = *(const u32x4*)(Vh + (size_t)(j * 64 + sv_kv) * DKn + sv_g * 8);
        vr1 = *(const u32x4*)(Vh + (size_t)(j * 64 + sv_kv) * DKn + sv_g * 8 + 32);
    };

    const int qg = qblk * 64 + w * 16 + q15;  // this lane's q row

    short8 qf[2];
#pragma unroll
    for (int ks = 0; ks < 2; ++ks)
        qf[ks] = __builtin_bit_cast(
            short8, *(const u32x4*)(Qh + (size_t)qg * DKn + ks * 32 + g * 8));

    f32x4 xacc[4] = {};  // O^T: xacc[mf][r] = O[q=q15][d=mf*16+4g+r]
    float m_run = -1e30f, l_run = 0.f;  // m_run in scaled (log2) domain

    load_kv(0);
    for (int j = 0; j <= qblk; ++j) {
        // ---- write staged KV regs to LDS ----
        {
            unsigned b0 = ((unsigned)(st_row * 128 + st_seg * 16)) ^
                          ((unsigned)(st_row & 7) << 4);
            unsigned b1 = ((unsigned)(st_row * 128 + (st_seg + 4) * 16)) ^
                          ((unsigned)(st_row & 7) << 4);
            *(u32x4*)((char*)Kt + b0) = kr0;
            *(u32x4*)((char*)Kt + b1) = kr1;
        }
#pragma unroll
        for (int r2 = 0; r2 < 2; ++r2) {
            u32x4 vvec = r2 ? vr1 : vr0;
            int dk0 = sv_g * 8 + r2 * 32;
#pragma unroll
            for (int i = 0; i < 4; ++i) {
                unsigned mine = vvec[i];
                unsigned theirs = (unsigned)__shfl_xor((int)mine, 1);
                int dk_abs = dk0 + 2 * i + sel;
                unsigned out = sel ? ((theirs >> 16) | (mine & 0xffff0000u))
                                   : ((mine & 0xffffu) | (theirs << 16));
                unsigned byteoff = ((unsigned)(dk_abs * 128) + kvp) ^
                                   ((unsigned)(dk_abs & 7) << 4);
                *(unsigned*)((char*)Vt + byteoff) = out;
            }
        }
        __syncthreads();

        // next tile's loads in flight under the compute
        if (j < qblk) load_kv(j + 1);

        // ---- QK^T (swapped): sacc rows = kv, cols = q ----
        f32x4 sacc[4] = {};
        __builtin_amdgcn_s_setprio(1);
#pragma unroll
        for (int mf = 0; mf < 4; ++mf) {
            int row = mf * 16 + q15;
#pragma unroll
            for (int ks = 0; ks < 2; ++ks) {
                unsigned byteoff = ((unsigned)(row * 128 + ks * 64 + g * 16)) ^
                                   ((unsigned)(row & 7) << 4);
                short8 kf =
                    __builtin_bit_cast(short8, *(const u32x4*)((char*)Kt + byteoff));
                sacc[mf] = __builtin_amdgcn_mfma_f32_16x16x32_bf16(kf, qf[ks],
                                                                   sacc[mf], 0, 0, 0);
            }
        }
        __builtin_amdgcn_s_setprio(0);

        // ---- mask + online softmax; max over RAW scores, scale via FMA ----
        float p[4][4];
        float pmax = -1e30f;
        const bool diag = (j == qblk);
#pragma unroll
        for (int mf = 0; mf < 4; ++mf)
#pragma unroll
            for (int r = 0; r < 4; ++r) {
                float sv = sacc[mf][r];
                if (diag) {
                    int kvg = j * 64 + mf * 16 + 4 * g + r;
                    if (kvg > qg) sv = -1e30f;
                }
                p[mf][r] = sv;
                pmax = fmaxf(pmax, sv);
            }
        pmax = fmaxf(pmax, __shfl_xor(pmax, 16));
        pmax = fmaxf(pmax, __shfl_xor(pmax, 32));
        float pmax_s = pmax * SCL;  // scaled-domain tile max
        if (__any(pmax_s > m_run + 8.f)) {  // T13 defer-max
            float mnew = fmaxf(m_run, pmax_s);
            float corr = exp2a(m_run - mnew);
            l_run *= corr;
#pragma unroll
            for (int mf = 0; mf < 4; ++mf)
#pragma unroll
                for (int r = 0; r < 4; ++r) xacc[mf][r] *= corr;
            m_run = mnew;
        }
        float lsum = 0.f;
#pragma unroll
        for (int mf = 0; mf < 4; ++mf)
#pragma unroll
            for (int r = 0; r < 4; ++r) {
                float e = exp2a(p[mf][r] * SCL - m_run);  // v_fma + v_exp
                p[mf][r] = e;
                lsum += e;
            }
        lsum += __shfl_xor(lsum, 16);
        lsum += __shfl_xor(lsum, 32);
        l_run += lsum;

        // ---- pack P; PV B-frag is lane-local (V columns pre-permuted) ----
        unsigned pkk[4][2];
#pragma unroll
        for (int mf = 0; mf < 4; ++mf) {
            pkk[mf][0] = pk2(p[mf][0], p[mf][1]);
            pkk[mf][1] = pk2(p[mf][2], p[mf][3]);
        }
        __builtin_amdgcn_s_setprio(1);
#pragma unroll
        for (int ks = 0; ks < 2; ++ks) {
            u32x4 tmp = {pkk[2 * ks][0], pkk[2 * ks][1], pkk[2 * ks + 1][0],
                         pkk[2 * ks + 1][1]};
            short8 pb = __builtin_bit_cast(short8, tmp);
#pragma unroll
            for (int mf = 0; mf < 4; ++mf) {
                int row = mf * 16 + q15;
                unsigned byteoff = ((unsigned)(row * 128 + ks * 64 + g * 16)) ^
                                   ((unsigned)(row & 7) << 4);
                short8 vf =
                    __builtin_bit_cast(short8, *(const u32x4*)((char*)Vt + byteoff));
                xacc[mf] = __builtin_amdgcn_mfma_f32_16x16x32_bf16(vf, pb,
                                                                   xacc[mf], 0, 0, 0);
            }
        }
        __builtin_amdgcn_s_setprio(0);
        __syncthreads();
    }

    // ---- epilogue: lane owns q=q15 row; 4x 8B stores ----
    float inv = 1.0f / l_run;
    size_t rowbase = (size_t)(b * Sn + qblk * 64 + w * 16 + q15) * Dn + h * 64;
#pragma unroll
    for (int mf = 0; mf < 4; ++mf) {
        unsigned w0 = pk2(xacc[mf][0] * inv, xacc[mf][1] * inv);
        unsigned w1 = pk2(xacc[mf][2] * inv, xacc[mf][3] * inv);
        uint2 val = {w0, w1};
        *(uint2*)(Xb + rowbase + mf * 16 + 4 * g) = val;
    }
}

// ---------------------------------------------------------------------------
// Launch. ws layout (bf16): Qb | Kb | Vb | Xb (16 MiB each) | Wb (8 MiB,
// 4 weight matrices bf16, if ws_size permits).
// ---------------------------------------------------------------------------
extern "C" void kernel_launch(void* const* d_in, const int* in_sizes, int n_in,
                              void* d_out, int out_size, void* d_ws, size_t ws_size,
                              hipStream_t stream) {
    (void)in_sizes; (void)n_in; (void)out_size;
    const float* q = (const float*)d_in[0];
    const float* k = (const float*)d_in[1];
    const float* v = (const float*)d_in[2];
    // d_in[3] = mask (causal tril; implemented analytically)
    const float* Wq = (const float*)d_in[4];
    const float* Wk = (const float*)d_in[5];
    const float* Wv = (const float*)d_in[6];
    const float* Wo = (const float*)d_in[7];

    unsigned short* Qb = (unsigned short*)d_ws;
    unsigned short* Kb = Qb + (size_t)Mrows * Dn;
    unsigned short* Vb = Kb + (size_t)Mrows * Dn;
    unsigned short* Xb = Vb + (size_t)Mrows * Dn;
    unsigned short* Wb = Xb + (size_t)Mrows * Dn;

    const size_t needW =
        (size_t)4 * Mrows * Dn * 2 + (size_t)4 * Dn * Dn * 2;  // 64 + 8 MiB
    const bool useWb = ws_size >= needW;

    dim3 blk(256);
    dim3 ggrid(Dn / 128, Mrows / 128);

    if (useWb) {
        cvt_w<<<dim3(Dn * Dn / (256 * 8), 4), blk, 0, stream>>>(Wq, Wk, Wv, Wo, Wb);
        const unsigned short* Wqb = Wb;
        const unsigned short* Wkb = Wb + (size_t)Dn * Dn;
        const unsigned short* Wvb = Wb + (size_t)2 * Dn * Dn;
        const unsigned short* Wob = Wb + (size_t)3 * Dn * Dn;
        gemm_nt<false, true, false><<<ggrid, blk, 0, stream>>>(q, Wqb, Qb);
        gemm_nt<false, true, false><<<ggrid, blk, 0, stream>>>(k, Wkb, Kb);
        gemm_nt<false, true, false><<<ggrid, blk, 0, stream>>>(v, Wvb, Vb);
        attn_fwd<<<dim3(NQB, Bn * Hn), blk, 0, stream>>>(Qb, Kb, Vb, Xb);
        gemm_nt<true, true, true><<<ggrid, blk, 0, stream>>>(Xb, Wob, d_out);
    } else {
        gemm_nt<false, false, false><<<ggrid, blk, 0, stream>>>(q, Wq, Qb);
        gemm_nt<false, false, false><<<ggrid, blk, 0, stream>>>(k, Wk, Kb);
        gemm_nt<false, false, false><<<ggrid, blk, 0, stream>>>(v, Wv, Vb);
        attn_fwd<<<dim3(NQB, Bn * Hn), blk, 0, stream>>>(Qb, Kb, Vb, Xb);
        gemm_nt<true, false, true><<<ggrid, blk, 0, stream>>>(Xb, Wo, d_out);
    }
}

// Round 14
// 228.102 us; speedup vs baseline: 1.2169x; 1.2169x over previous
//
#include <hip/hip_runtime.h>
#include <hip/hip_bf16.h>

// Problem constants
constexpr int Bn = 4, Sn = 2048, Dn = 1024, Hn = 16, DKn = 64;
constexpr int Mrows = Bn * Sn;  // 8192
constexpr int NQB = Sn / 64;    // 32 q-chunks of 64 rows

typedef __attribute__((ext_vector_type(8))) short short8;
typedef __attribute__((ext_vector_type(4))) float f32x4;
typedef __attribute__((ext_vector_type(4))) unsigned int u32x4;

#define DEV __device__ __forceinline__

// fp32 -> bf16 RNE, scalar (epilogue scatter only)
DEV unsigned short f2bf(float f) {
    unsigned u = __builtin_bit_cast(unsigned, f);
    u += 0x7FFFu + ((u >> 16) & 1u);
    return (unsigned short)(u >> 16);
}
// fp32 pair -> packed bf16x2 via v_cvt_pk_bf16_f32 (hardware RNE)
DEV unsigned pk2(float a, float b) {
    __hip_bfloat162 h = __float22bfloat162_rn(float2{a, b});
    unsigned u;
    __builtin_memcpy(&u, &h, 4);
    return u;
}
// 2^x via v_exp_f32
DEV float exp2a(float x) {
    float r;
    asm("v_exp_f32 %0, %1" : "=v"(r) : "v"(x));
    return r;
}

// ---------------------------------------------------------------------------
// Weights fp32 -> bf16, one matrix per blockIdx.y. 8 elems/thread.
// ---------------------------------------------------------------------------
__global__ __launch_bounds__(256) void cvt_w(const float* __restrict__ W0,
                                             const float* __restrict__ W1,
                                             const float* __restrict__ W2,
                                             const float* __restrict__ W3,
                                             unsigned short* __restrict__ Out) {
    const float* src = blockIdx.y == 0 ? W0
                     : blockIdx.y == 1 ? W1
                     : blockIdx.y == 2 ? W2 : W3;
    size_t off = ((size_t)blockIdx.x * 256 + threadIdx.x) * 8;
    const float4* s = (const float4*)(src + off);
    float4 a = s[0], b = s[1];
    u32x4 p = {pk2(a.x, a.y), pk2(a.z, a.w), pk2(b.x, b.y), pk2(b.z, b.w)};
    *(u32x4*)(Out + (size_t)blockIdx.y * (Dn * Dn) + off) = p;
}

// ---------------------------------------------------------------------------
// GEMM body: C[m,n] = sum_k A[m,k] * W[n,k]  (y = x @ W^T), M=8192, N=K=1024.
// 128x128 tile, BK=32, 256 threads (4 waves, 2x2 wave grid, 64x64 per wave).
// XCD-AWARE REMAP (R12 win): all 8 n-blocks of one A-panel share bid%8 ->
// same XCD L2; per-XCD A set = 4MB = L2 size. Bijective.
// Reg-prefetch of next K-step during compute. A/B optionally bf16.
// ---------------------------------------------------------------------------
template <bool ABF16, bool BBF16, bool OUTF32>
DEV void gemm_body(const void* __restrict__ Ap, const void* __restrict__ Bw,
                   void* __restrict__ Out) {
    __shared__ alignas(16) unsigned short As[128 * 40];
    __shared__ alignas(16) unsigned short Bs[128 * 40];

    const int tid = threadIdx.x;
    const int bid = (int)(blockIdx.y * gridDim.x + blockIdx.x);
    const int xcd = bid & 7;
    const int jj = bid >> 3;
    const int m0 = (xcd + ((jj & 7) << 3)) * 128;  // 64 m-panels
    const int n0 = (jj >> 3) * 128;                // 8 n-panels
    const int lane = tid & 63;
    const int w = tid >> 6;
    const int wm = (w >> 1) * 64, wn = (w & 1) * 64;
    const int g = lane >> 4, q15 = lane & 15;

    f32x4 acc[4][4] = {};

    const int srow = tid >> 1, shalf = tid & 1;

    const float* Af = (const float*)Ap;
    const unsigned short* Ab = (const unsigned short*)Ap;
    const float* Bf = (const float*)Bw;
    const unsigned short* Bb = (const unsigned short*)Bw;

    float4 fa0, fa1, fa2, fa3, fb0, fb1, fb2, fb3;
    u32x4 ua0, ua1, ub0, ub1;

    auto loadA = [&](int kk) {
        if constexpr (ABF16) {
            const u32x4* s =
                (const u32x4*)(Ab + (size_t)(m0 + srow) * Dn + kk + shalf * 16);
            ua0 = s[0];
            ua1 = s[1];
        } else {
            const float4* s =
                (const float4*)(Af + (size_t)(m0 + srow) * Dn + kk + shalf * 16);
            fa0 = s[0]; fa1 = s[1]; fa2 = s[2]; fa3 = s[3];
        }
    };
    auto loadB = [&](int kk) {
        if constexpr (BBF16) {
            const u32x4* s =
                (const u32x4*)(Bb + (size_t)(n0 + srow) * Dn + kk + shalf * 16);
            ub0 = s[0];
            ub1 = s[1];
        } else {
            const float4* s =
                (const float4*)(Bf + (size_t)(n0 + srow) * Dn + kk + shalf * 16);
            fb0 = s[0]; fb1 = s[1]; fb2 = s[2]; fb3 = s[3];
        }
    };
    auto store = [&]() {
        u32x4* da = (u32x4*)(&As[srow * 40 + shalf * 16]);
        if constexpr (ABF16) {
            da[0] = ua0;
            da[1] = ua1;
        } else {
            u32x4 p0 = {pk2(fa0.x, fa0.y), pk2(fa0.z, fa0.w), pk2(fa1.x, fa1.y),
                        pk2(fa1.z, fa1.w)};
            u32x4 p1 = {pk2(fa2.x, fa2.y), pk2(fa2.z, fa2.w), pk2(fa3.x, fa3.y),
                        pk2(fa3.z, fa3.w)};
            da[0] = p0;
            da[1] = p1;
        }
        u32x4* db = (u32x4*)(&Bs[srow * 40 + shalf * 16]);
        if constexpr (BBF16) {
            db[0] = ub0;
            db[1] = ub1;
        } else {
            u32x4 q0 = {pk2(fb0.x, fb0.y), pk2(fb0.z, fb0.w), pk2(fb1.x, fb1.y),
                        pk2(fb1.z, fb1.w)};
            u32x4 q1 = {pk2(fb2.x, fb2.y), pk2(fb2.z, fb2.w), pk2(fb3.x, fb3.y),
                        pk2(fb3.z, fb3.w)};
            db[0] = q0;
            db[1] = q1;
        }
    };

    loadA(0);
    loadB(0);
    for (int kk = 0; kk < Dn; kk += 32) {
        store();
        __syncthreads();
        if (kk + 32 < Dn) {
            loadA(kk + 32);
            loadB(kk + 32);
        }

        short8 af[4], bf[4];
#pragma unroll
        for (int mf = 0; mf < 4; ++mf)
            af[mf] = __builtin_bit_cast(
                short8, *(const u32x4*)(&As[(wm + mf * 16 + q15) * 40 + g * 8]));
#pragma unroll
        for (int nf = 0; nf < 4; ++nf)
            bf[nf] = __builtin_bit_cast(
                short8, *(const u32x4*)(&Bs[(wn + nf * 16 + q15) * 40 + g * 8]));
#pragma unroll
        for (int mf = 0; mf < 4; ++mf)
#pragma unroll
            for (int nf = 0; nf < 4; ++nf)
                acc[mf][nf] = __builtin_amdgcn_mfma_f32_16x16x32_bf16(
                    af[mf], bf[nf], acc[mf][nf], 0, 0, 0);
        __syncthreads();
    }

#pragma unroll
    for (int mf = 0; mf < 4; ++mf)
#pragma unroll
        for (int nf = 0; nf < 4; ++nf)
#pragma unroll
            for (int r = 0; r < 4; ++r) {
                int m = m0 + wm + mf * 16 + 4 * g + r;
                int n = n0 + wn + nf * 16 + q15;
                float val = acc[mf][nf][r];
                if (OUTF32) {
                    ((float*)Out)[(size_t)m * Dn + n] = val;
                } else {
                    int b = m >> 11, s = m & (Sn - 1);
                    int h = n >> 6, dk = n & 63;
                    ((unsigned short*)Out)[(((size_t)(b * Hn + h) * Sn + s) << 6) +
                                           dk] = f2bf(val);
                }
            }
}

template <bool ABF16, bool BBF16, bool OUTF32>
__global__ __launch_bounds__(256) void gemm_nt(const void* __restrict__ Ap,
                                               const void* __restrict__ Bw,
                                               void* __restrict__ Out) {
    gemm_body<ABF16, BBF16, OUTF32>(Ap, Bw, Out);
}

// ---------------------------------------------------------------------------
// Causal flash attention — R12 paired structure (R13 unpaired grid regressed
// 40%: load imbalance tail; reverted). Block p runs chunk 31-p then chunk p
// (uniform 33 KV-iterations). 256 threads = 4 waves, 16 q rows/wave.
// Single-buffer LDS:
//   Kt: [64kv][64dk] XOR-swizzled (byte ^= (row&7)<<4)
//   Vt: [64dk][64 kv-PERMUTED] transposed at staging (R11 win): col_new(kv)
//   = (kv&32)|((kv&12)<<1)|((kv&16)>>2)|(kv&3) makes the PV B-fragment the
//   lane's own packed pkk regs (no P-gather shuffles); bit0 preserved.
// QK^T swapped (sacc rows=kv, cols=q). Softmax: max over RAW scores (scale
// commutes with max), SCL folded into exp FMA. T13 defer-max; T14
// reg-prefetch. NEW: softmax denominator via MFMA with constant all-ones A
// fragment — l = sum_kv P^T[kv][q] lands in xl[.] per lane; removes the
// 15-add + 2-bpermute serial lsum chain (matrix pipe is 12% utilized).
// l now derives from bf16-rounded P (same as PV numerator — matched ratio).
// No setprio (m190/R13: hurts barrier-locked lockstep waves).
// NOTE: no min-waves in launch_bounds (R7: register cap -> 456MB spill).
// ---------------------------------------------------------------------------
__global__ __launch_bounds__(256) void attn_fwd(
    const unsigned short* __restrict__ Qb, const unsigned short* __restrict__ Kb,
    const unsigned short* __restrict__ Vb, unsigned short* __restrict__ Xb) {
    __shared__ alignas(16) unsigned short Kt[64 * 64];
    __shared__ alignas(16) unsigned short Vt[64 * 64];

    constexpr float SCL = 0.18033688f;  // 0.125 * log2(e)

    const int tid = threadIdx.x;
    const int pair = blockIdx.x;  // 0..15
    const int bh = blockIdx.y;
    const int b = bh >> 4, h = bh & 15;
    const int lane = tid & 63, w = tid >> 6;
    const int g = lane >> 4, q15 = lane & 15;

    const unsigned short* Qh = Qb + (size_t)bh * Sn * DKn;
    const unsigned short* Kh = Kb + (size_t)bh * Sn * DKn;
    const unsigned short* Vh = Vb + (size_t)bh * Sn * DKn;

    const int st_row = tid >> 2, st_seg = tid & 3;  // K staging
    const int sv_kv = tid & 63, sv_g = tid >> 6;    // V staging
    const int sel = sv_kv & 1;
    // permuted byte col base in Vt (bit0 of kv preserved by col_new)
    const int kv_even = sv_kv & ~1;
    const unsigned kvp = (unsigned)(((kv_even & 32) | ((kv_even & 12) << 1) |
                                     ((kv_even & 16) >> 2) | (kv_even & 3)) *
                                    2);

    // constant all-ones bf16 A-fragment for the denominator MFMA
    const short8 ones = {0x3F80, 0x3F80, 0x3F80, 0x3F80,
                         0x3F80, 0x3F80, 0x3F80, 0x3F80};

    u32x4 kr0, kr1, vr0, vr1;  // prefetch registers
    auto load_kv = [&](int j) {
        kr0 = *(const u32x4*)(Kh + (size_t)(j * 64 + st_row) * DKn + st_seg * 8);
        kr1 = *(const u32x4*)(Kh + (size_t)(j * 64 + st_row) * DKn +
                              (st_seg + 4) * 8);
        vr0 = *(const u32x4*)(Vh + (size_t)(j * 64 + sv_kv) * DKn + sv_g * 8);
        vr1 = *(const u32x4*)(Vh + (size_t)(j * 64 + sv_kv) * DKn + sv_g * 8 + 32);
    };

    for (int hp = 0; hp < 2; ++hp) {
        const int qblk = hp == 0 ? (NQB - 1 - pair) : pair;
        const int qg = qblk * 64 + w * 16 + q15;  // this lane's q row

        short8 qf[2];
#pragma unroll
        for (int ks = 0; ks < 2; ++ks)
            qf[ks] = __builtin_bit_cast(
                short8, *(const u32x4*)(Qh + (size_t)qg * DKn + ks * 32 + g * 8));

        f32x4 xacc[4] = {};  // O^T: xacc[mf][r] = O[q=q15][d=mf*16+4g+r]
        f32x4 xl = {};       // denominator accumulator (all r identical)
        float m_run = -1e30f;  // running max, scaled (log2) domain

        load_kv(0);
        for (int j = 0; j <= qblk; ++j) {
            // ---- write staged KV regs to LDS ----
            {
                unsigned b0 = ((unsigned)(st_row * 128 + st_seg * 16)) ^
                              ((unsigned)(st_row & 7) << 4);
                unsigned b1 = ((unsigned)(st_row * 128 + (st_seg + 4) * 16)) ^
                              ((unsigned)(st_row & 7) << 4);
                *(u32x4*)((char*)Kt + b0) = kr0;
                *(u32x4*)((char*)Kt + b1) = kr1;
            }
#pragma unroll
            for (int r2 = 0; r2 < 2; ++r2) {
                u32x4 vvec = r2 ? vr1 : vr0;
                int dk0 = sv_g * 8 + r2 * 32;
#pragma unroll
                for (int i = 0; i < 4; ++i) {
                    unsigned mine = vvec[i];
                    unsigned theirs = (unsigned)__shfl_xor((int)mine, 1);
                    int dk_abs = dk0 + 2 * i + sel;
                    unsigned out = sel ? ((theirs >> 16) | (mine & 0xffff0000u))
                                       : ((mine & 0xffffu) | (theirs << 16));
                    unsigned byteoff = ((unsigned)(dk_abs * 128) + kvp) ^
                                       ((unsigned)(dk_abs & 7) << 4);
                    *(unsigned*)((char*)Vt + byteoff) = out;
                }
            }
            __syncthreads();

            // next tile's loads in flight under the compute
            if (j < qblk) load_kv(j + 1);

            // ---- QK^T (swapped): sacc rows = kv, cols = q ----
            f32x4 sacc[4] = {};
#pragma unroll
            for (int mf = 0; mf < 4; ++mf) {
                int row = mf * 16 + q15;
#pragma unroll
                for (int ks = 0; ks < 2; ++ks) {
                    unsigned byteoff = ((unsigned)(row * 128 + ks * 64 + g * 16)) ^
                                       ((unsigned)(row & 7) << 4);
                    short8 kf = __builtin_bit_cast(
                        short8, *(const u32x4*)((char*)Kt + byteoff));
                    sacc[mf] = __builtin_amdgcn_mfma_f32_16x16x32_bf16(
                        kf, qf[ks], sacc[mf], 0, 0, 0);
                }
            }

            // ---- mask + online softmax; max over RAW scores, SCL via FMA ----
            float p[4][4];
            float pmax = -1e30f;
            const bool diag = (j == qblk);
#pragma unroll
            for (int mf = 0; mf < 4; ++mf)
#pragma unroll
                for (int r = 0; r < 4; ++r) {
                    float sv = sacc[mf][r];
                    if (diag) {
                        int kvg = j * 64 + mf * 16 + 4 * g + r;
                        if (kvg > qg) sv = -1e30f;
                    }
                    p[mf][r] = sv;
                    pmax = fmaxf(pmax, sv);
                }
            pmax = fmaxf(pmax, __shfl_xor(pmax, 16));
            pmax = fmaxf(pmax, __shfl_xor(pmax, 32));
            float pmax_s = pmax * SCL;  // scaled-domain tile max
            if (__any(pmax_s > m_run + 8.f)) {  // T13 defer-max
                float mnew = fmaxf(m_run, pmax_s);
                float corr = exp2a(m_run - mnew);
#pragma unroll
                for (int mf = 0; mf < 4; ++mf)
#pragma unroll
                    for (int r = 0; r < 4; ++r) xacc[mf][r] *= corr;
#pragma unroll
                for (int r = 0; r < 4; ++r) xl[r] *= corr;
                m_run = mnew;
            }
#pragma unroll
            for (int mf = 0; mf < 4; ++mf)
#pragma unroll
                for (int r = 0; r < 4; ++r)
                    p[mf][r] = exp2a(p[mf][r] * SCL - m_run);  // v_fma + v_exp

            // ---- pack P; PV B-frag is lane-local (V columns pre-permuted) ----
            unsigned pkk[4][2];
#pragma unroll
            for (int mf = 0; mf < 4; ++mf) {
                pkk[mf][0] = pk2(p[mf][0], p[mf][1]);
                pkk[mf][1] = pk2(p[mf][2], p[mf][3]);
            }
#pragma unroll
            for (int ks = 0; ks < 2; ++ks) {
                u32x4 tmp = {pkk[2 * ks][0], pkk[2 * ks][1], pkk[2 * ks + 1][0],
                             pkk[2 * ks + 1][1]};
                short8 pb = __builtin_bit_cast(short8, tmp);
                // denominator: l += sum_kv P^T[kv][q] via ones-A MFMA
                xl = __builtin_amdgcn_mfma_f32_16x16x32_bf16(ones, pb, xl, 0, 0, 0);
#pragma unroll
                for (int mf = 0; mf < 4; ++mf) {
                    int row = mf * 16 + q15;
                    unsigned byteoff = ((unsigned)(row * 128 + ks * 64 + g * 16)) ^
                                       ((unsigned)(row & 7) << 4);
                    short8 vf = __builtin_bit_cast(
                        short8, *(const u32x4*)((char*)Vt + byteoff));
                    xacc[mf] = __builtin_amdgcn_mfma_f32_16x16x32_bf16(
                        vf, pb, xacc[mf], 0, 0, 0);
                }
            }
            __syncthreads();
        }

        // ---- epilogue: lane owns q=q15 row; 4x 8B stores ----
        float inv = 1.0f / xl[0];
        size_t rowbase = (size_t)(b * Sn + qblk * 64 + w * 16 + q15) * Dn + h * 64;
#pragma unroll
        for (int mf = 0; mf < 4; ++mf) {
            unsigned w0 = pk2(xacc[mf][0] * inv, xacc[mf][1] * inv);
            unsigned w1 = pk2(xacc[mf][2] * inv, xacc[mf][3] * inv);
            uint2 val = {w0, w1};
            *(uint2*)(Xb + rowbase + mf * 16 + 4 * g) = val;
        }
    }
}

// ---------------------------------------------------------------------------
// Launch. ws layout (bf16): Qb | Kb | Vb | Xb (16 MiB each) | Wb (8 MiB,
// 4 weight matrices bf16, if ws_size permits).
// ---------------------------------------------------------------------------
extern "C" void kernel_launch(void* const* d_in, const int* in_sizes, int n_in,
                              void* d_out, int out_size, void* d_ws, size_t ws_size,
                              hipStream_t stream) {
    (void)in_sizes; (void)n_in; (void)out_size;
    const float* q = (const float*)d_in[0];
    const float* k = (const float*)d_in[1];
    const float* v = (const float*)d_in[2];
    // d_in[3] = mask (causal tril; implemented analytically)
    const float* Wq = (const float*)d_in[4];
    const float* Wk = (const float*)d_in[5];
    const float* Wv = (const float*)d_in[6];
    const float* Wo = (const float*)d_in[7];

    unsigned short* Qb = (unsigned short*)d_ws;
    unsigned short* Kb = Qb + (size_t)Mrows * Dn;
    unsigned short* Vb = Kb + (size_t)Mrows * Dn;
    unsigned short* Xb = Vb + (size_t)Mrows * Dn;
    unsigned short* Wb = Xb + (size_t)Mrows * Dn;

    const size_t needW =
        (size_t)4 * Mrows * Dn * 2 + (size_t)4 * Dn * Dn * 2;  // 64 + 8 MiB
    const bool useWb = ws_size >= needW;

    dim3 blk(256);
    dim3 ggrid(Dn / 128, Mrows / 128);

    if (useWb) {
        cvt_w<<<dim3(Dn * Dn / (256 * 8), 4), blk, 0, stream>>>(Wq, Wk, Wv, Wo, Wb);
        const unsigned short* Wqb = Wb;
        const unsigned short* Wkb = Wb + (size_t)Dn * Dn;
        const unsigned short* Wvb = Wb + (size_t)2 * Dn * Dn;
        const unsigned short* Wob = Wb + (size_t)3 * Dn * Dn;
        gemm_nt<false, true, false><<<ggrid, blk, 0, stream>>>(q, Wqb, Qb);
        gemm_nt<false, true, false><<<ggrid, blk, 0, stream>>>(k, Wkb, Kb);
        gemm_nt<false, true, false><<<ggrid, blk, 0, stream>>>(v, Wvb, Vb);
        attn_fwd<<<dim3(NQB / 2, Bn * Hn), blk, 0, stream>>>(Qb, Kb, Vb, Xb);
        gemm_nt<true, true, true><<<ggrid, blk, 0, stream>>>(Xb, Wob, d_out);
    } else {
        gemm_nt<false, false, false><<<ggrid, blk, 0, stream>>>(q, Wq, Qb);
        gemm_nt<false, false, false><<<ggrid, blk, 0, stream>>>(k, Wk, Kb);
        gemm_nt<false, false, false><<<ggrid, blk, 0, stream>>>(v, Wv, Vb);
        attn_fwd<<<dim3(NQB / 2, Bn * Hn), blk, 0, stream>>>(Qb, Kb, Vb, Xb);
        gemm_nt<true, false, true><<<ggrid, blk, 0, stream>>>(Xb, Wo, d_out);
    }
}

// Round 15
// 220.087 us; speedup vs baseline: 1.2612x; 1.0364x over previous
//
#include <hip/hip_runtime.h>
#include <hip/hip_bf16.h>

// Problem constants
constexpr int Bn = 4, Sn = 2048, Dn = 1024, Hn = 16, DKn = 64;
constexpr int Mrows = Bn * Sn;  // 8192
constexpr int NQB = Sn / 64;    // 32 q-chunks of 64 rows

typedef __attribute__((ext_vector_type(8))) short short8;
typedef __attribute__((ext_vector_type(4))) float f32x4;
typedef __attribute__((ext_vector_type(4))) unsigned int u32x4;

#define DEV __device__ __forceinline__

// fp32 -> bf16 RNE, scalar (epilogue scatter only)
DEV unsigned short f2bf(float f) {
    unsigned u = __builtin_bit_cast(unsigned, f);
    u += 0x7FFFu + ((u >> 16) & 1u);
    return (unsigned short)(u >> 16);
}
// fp32 pair -> packed bf16x2 via v_cvt_pk_bf16_f32 (hardware RNE)
DEV unsigned pk2(float a, float b) {
    __hip_bfloat162 h = __float22bfloat162_rn(float2{a, b});
    unsigned u;
    __builtin_memcpy(&u, &h, 4);
    return u;
}
// 2^x via v_exp_f32
DEV float exp2a(float x) {
    float r;
    asm("v_exp_f32 %0, %1" : "=v"(r) : "v"(x));
    return r;
}

// ---------------------------------------------------------------------------
// Weights fp32 -> bf16, one matrix per blockIdx.y. 8 elems/thread.
// ---------------------------------------------------------------------------
__global__ __launch_bounds__(256) void cvt_w(const float* __restrict__ W0,
                                             const float* __restrict__ W1,
                                             const float* __restrict__ W2,
                                             const float* __restrict__ W3,
                                             unsigned short* __restrict__ Out) {
    const float* src = blockIdx.y == 0 ? W0
                     : blockIdx.y == 1 ? W1
                     : blockIdx.y == 2 ? W2 : W3;
    size_t off = ((size_t)blockIdx.x * 256 + threadIdx.x) * 8;
    const float4* s = (const float4*)(src + off);
    float4 a = s[0], b = s[1];
    u32x4 p = {pk2(a.x, a.y), pk2(a.z, a.w), pk2(b.x, b.y), pk2(b.z, b.w)};
    *(u32x4*)(Out + (size_t)blockIdx.y * (Dn * Dn) + off) = p;
}

// ---------------------------------------------------------------------------
// GEMM body: C[m,n] = sum_k A[m,k] * W[n,k]  (y = x @ W^T), M=8192, N=K=1024.
// 128x128 tile, BK=32, **512 threads (8 waves, 2x4 wave grid, 32x64/wave)**
// — R14: grid 512 blocks was 2 blocks/CU = 8 waves/CU (25% cap); 512-thread
// blocks double resident waves to 16/CU at identical tile/traffic. Per-wave
// acc halves to 8 f32x4; per-thread staging halves to 1 u32x4 per tile.
// XCD-AWARE REMAP (R12 win): all 8 n-blocks of one A-panel share bid%8 ->
// same XCD L2; per-XCD A set = 4MB = L2 size. Bijective.
// Reg-prefetch of next K-step during compute. A/B optionally bf16.
// ---------------------------------------------------------------------------
template <bool ABF16, bool BBF16, bool OUTF32>
DEV void gemm_body(const void* __restrict__ Ap, const void* __restrict__ Bw,
                   void* __restrict__ Out) {
    __shared__ alignas(16) unsigned short As[128 * 40];
    __shared__ alignas(16) unsigned short Bs[128 * 40];

    const int tid = threadIdx.x;  // 0..511
    const int bid = (int)(blockIdx.y * gridDim.x + blockIdx.x);
    const int xcd = bid & 7;
    const int jj = bid >> 3;
    const int m0 = (xcd + ((jj & 7) << 3)) * 128;  // 64 m-panels
    const int n0 = (jj >> 3) * 128;                // 8 n-panels
    const int lane = tid & 63;
    const int w = tid >> 6;                 // 0..7
    const int wm = (w >> 1) * 32;           // 4 m-waves x 32 rows
    const int wn = (w & 1) * 64;            // 2 n-waves x 64 cols
    const int g = lane >> 4, q15 = lane & 15;

    f32x4 acc[2][4] = {};

    const int srow = tid >> 2, sseg = tid & 3;  // 128 rows x 4 segs of 8 elems

    const float* Af = (const float*)Ap;
    const unsigned short* Ab = (const unsigned short*)Ap;
    const float* Bf = (const float*)Bw;
    const unsigned short* Bb = (const unsigned short*)Bw;

    float4 fa0, fa1, fb0, fb1;
    u32x4 ua0, ub0;

    auto loadA = [&](int kk) {
        if constexpr (ABF16) {
            ua0 = *(const u32x4*)(Ab + (size_t)(m0 + srow) * Dn + kk + sseg * 8);
        } else {
            const float4* s =
                (const float4*)(Af + (size_t)(m0 + srow) * Dn + kk + sseg * 8);
            fa0 = s[0];
            fa1 = s[1];
        }
    };
    auto loadB = [&](int kk) {
        if constexpr (BBF16) {
            ub0 = *(const u32x4*)(Bb + (size_t)(n0 + srow) * Dn + kk + sseg * 8);
        } else {
            const float4* s =
                (const float4*)(Bf + (size_t)(n0 + srow) * Dn + kk + sseg * 8);
            fb0 = s[0];
            fb1 = s[1];
        }
    };
    auto store = [&]() {
        u32x4* da = (u32x4*)(&As[srow * 40 + sseg * 8]);
        if constexpr (ABF16) {
            da[0] = ua0;
        } else {
            u32x4 p0 = {pk2(fa0.x, fa0.y), pk2(fa0.z, fa0.w), pk2(fa1.x, fa1.y),
                        pk2(fa1.z, fa1.w)};
            da[0] = p0;
        }
        u32x4* db = (u32x4*)(&Bs[srow * 40 + sseg * 8]);
        if constexpr (BBF16) {
            db[0] = ub0;
        } else {
            u32x4 q0 = {pk2(fb0.x, fb0.y), pk2(fb0.z, fb0.w), pk2(fb1.x, fb1.y),
                        pk2(fb1.z, fb1.w)};
            db[0] = q0;
        }
    };

    loadA(0);
    loadB(0);
    for (int kk = 0; kk < Dn; kk += 32) {
        store();
        __syncthreads();
        if (kk + 32 < Dn) {
            loadA(kk + 32);
            loadB(kk + 32);
        }

        short8 af[2], bf[4];
#pragma unroll
        for (int mf = 0; mf < 2; ++mf)
            af[mf] = __builtin_bit_cast(
                short8, *(const u32x4*)(&As[(wm + mf * 16 + q15) * 40 + g * 8]));
#pragma unroll
        for (int nf = 0; nf < 4; ++nf)
            bf[nf] = __builtin_bit_cast(
                short8, *(const u32x4*)(&Bs[(wn + nf * 16 + q15) * 40 + g * 8]));
#pragma unroll
        for (int mf = 0; mf < 2; ++mf)
#pragma unroll
            for (int nf = 0; nf < 4; ++nf)
                acc[mf][nf] = __builtin_amdgcn_mfma_f32_16x16x32_bf16(
                    af[mf], bf[nf], acc[mf][nf], 0, 0, 0);
        __syncthreads();
    }

#pragma unroll
    for (int mf = 0; mf < 2; ++mf)
#pragma unroll
        for (int nf = 0; nf < 4; ++nf)
#pragma unroll
            for (int r = 0; r < 4; ++r) {
                int m = m0 + wm + mf * 16 + 4 * g + r;
                int n = n0 + wn + nf * 16 + q15;
                float val = acc[mf][nf][r];
                if (OUTF32) {
                    ((float*)Out)[(size_t)m * Dn + n] = val;
                } else {
                    int b = m >> 11, s = m & (Sn - 1);
                    int h = n >> 6, dk = n & 63;
                    ((unsigned short*)Out)[(((size_t)(b * Hn + h) * Sn + s) << 6) +
                                           dk] = f2bf(val);
                }
            }
}

template <bool ABF16, bool BBF16, bool OUTF32>
__global__ __launch_bounds__(512) void gemm_nt(const void* __restrict__ Ap,
                                               const void* __restrict__ Bw,
                                               void* __restrict__ Out) {
    gemm_body<ABF16, BBF16, OUTF32>(Ap, Bw, Out);
}

// ---------------------------------------------------------------------------
// Causal flash attention — R12 paired structure. Block p runs chunk 31-p
// then chunk p (uniform 33 KV-iterations). 256 threads = 4 waves, 16 q
// rows/wave. Single-buffer LDS:
//   Kt: [64kv][64dk] XOR-swizzled (byte ^= (row&7)<<4)
//   Vt: [64dk][64 kv-PERMUTED] transposed at staging (R11 win): col_new(kv)
//   = (kv&32)|((kv&12)<<1)|((kv&16)>>2)|(kv&3) makes the PV B-fragment the
//   lane's own packed pkk regs (no P-gather shuffles); bit0 preserved.
// QK^T swapped (sacc rows=kv, cols=q). Softmax: max over RAW scores, SCL
// folded into exp FMA; T13 defer-max; T14 reg-prefetch; denominator via
// ones-A MFMA (R14: VALUBusy -5%, neutral time — kept, frees VALU).
// NOTE: no min-waves in launch_bounds (R7: register cap -> 456MB spill).
// ---------------------------------------------------------------------------
__global__ __launch_bounds__(256) void attn_fwd(
    const unsigned short* __restrict__ Qb, const unsigned short* __restrict__ Kb,
    const unsigned short* __restrict__ Vb, unsigned short* __restrict__ Xb) {
    __shared__ alignas(16) unsigned short Kt[64 * 64];
    __shared__ alignas(16) unsigned short Vt[64 * 64];

    constexpr float SCL = 0.18033688f;  // 0.125 * log2(e)

    const int tid = threadIdx.x;
    const int pair = blockIdx.x;  // 0..15
    const int bh = blockIdx.y;
    const int b = bh >> 4, h = bh & 15;
    const int lane = tid & 63, w = tid >> 6;
    const int g = lane >> 4, q15 = lane & 15;

    const unsigned short* Qh = Qb + (size_t)bh * Sn * DKn;
    const unsigned short* Kh = Kb + (size_t)bh * Sn * DKn;
    const unsigned short* Vh = Vb + (size_t)bh * Sn * DKn;

    const int st_row = tid >> 2, st_seg = tid & 3;  // K staging
    const int sv_kv = tid & 63, sv_g = tid >> 6;    // V staging
    const int sel = sv_kv & 1;
    // permuted byte col base in Vt (bit0 of kv preserved by col_new)
    const int kv_even = sv_kv & ~1;
    const unsigned kvp = (unsigned)(((kv_even & 32) | ((kv_even & 12) << 1) |
                                     ((kv_even & 16) >> 2) | (kv_even & 3)) *
                                    2);

    // constant all-ones bf16 A-fragment for the denominator MFMA
    const short8 ones = {0x3F80, 0x3F80, 0x3F80, 0x3F80,
                         0x3F80, 0x3F80, 0x3F80, 0x3F80};

    u32x4 kr0, kr1, vr0, vr1;  // prefetch registers
    auto load_kv = [&](int j) {
        kr0 = *(const u32x4*)(Kh + (size_t)(j * 64 + st_row) * DKn + st_seg * 8);
        kr1 = *(const u32x4*)(Kh + (size_t)(j * 64 + st_row) * DKn +
                              (st_seg + 4) * 8);
        vr0 = *(const u32x4*)(Vh + (size_t)(j * 64 + sv_kv) * DKn + sv_g * 8);
        vr1 = *(const u32x4*)(Vh + (size_t)(j * 64 + sv_kv) * DKn + sv_g * 8 + 32);
    };

    for (int hp = 0; hp < 2; ++hp) {
        const int qblk = hp == 0 ? (NQB - 1 - pair) : pair;
        const int qg = qblk * 64 + w * 16 + q15;  // this lane's q row

        short8 qf[2];
#pragma unroll
        for (int ks = 0; ks < 2; ++ks)
            qf[ks] = __builtin_bit_cast(
                short8, *(const u32x4*)(Qh + (size_t)qg * DKn + ks * 32 + g * 8));

        f32x4 xacc[4] = {};  // O^T: xacc[mf][r] = O[q=q15][d=mf*16+4g+r]
        f32x4 xl = {};       // denominator accumulator (all r identical)
        float m_run = -1e30f;  // running max, scaled (log2) domain

        load_kv(0);
        for (int j = 0; j <= qblk; ++j) {
            // ---- write staged KV regs to LDS ----
            {
                unsigned b0 = ((unsigned)(st_row * 128 + st_seg * 16)) ^
                              ((unsigned)(st_row & 7) << 4);
                unsigned b1 = ((unsigned)(st_row * 128 + (st_seg + 4) * 16)) ^
                              ((unsigned)(st_row & 7) << 4);
                *(u32x4*)((char*)Kt + b0) = kr0;
                *(u32x4*)((char*)Kt + b1) = kr1;
            }
#pragma unroll
            for (int r2 = 0; r2 < 2; ++r2) {
                u32x4 vvec = r2 ? vr1 : vr0;
                int dk0 = sv_g * 8 + r2 * 32;
#pragma unroll
                for (int i = 0; i < 4; ++i) {
                    unsigned mine = vvec[i];
                    unsigned theirs = (unsigned)__shfl_xor((int)mine, 1);
                    int dk_abs = dk0 + 2 * i + sel;
                    unsigned out = sel ? ((theirs >> 16) | (mine & 0xffff0000u))
                                       : ((mine & 0xffffu) | (theirs << 16));
                    unsigned byteoff = ((unsigned)(dk_abs * 128) + kvp) ^
                                       ((unsigned)(dk_abs & 7) << 4);
                    *(unsigned*)((char*)Vt + byteoff) = out;
                }
            }
            __syncthreads();

            // next tile's loads in flight under the compute
            if (j < qblk) load_kv(j + 1);

            // ---- QK^T (swapped): sacc rows = kv, cols = q ----
            f32x4 sacc[4] = {};
#pragma unroll
            for (int mf = 0; mf < 4; ++mf) {
                int row = mf * 16 + q15;
#pragma unroll
                for (int ks = 0; ks < 2; ++ks) {
                    unsigned byteoff = ((unsigned)(row * 128 + ks * 64 + g * 16)) ^
                                       ((unsigned)(row & 7) << 4);
                    short8 kf = __builtin_bit_cast(
                        short8, *(const u32x4*)((char*)Kt + byteoff));
                    sacc[mf] = __builtin_amdgcn_mfma_f32_16x16x32_bf16(
                        kf, qf[ks], sacc[mf], 0, 0, 0);
                }
            }

            // ---- mask + online softmax; max over RAW scores, SCL via FMA ----
            float p[4][4];
            float pmax = -1e30f;
            const bool diag = (j == qblk);
#pragma unroll
            for (int mf = 0; mf < 4; ++mf)
#pragma unroll
                for (int r = 0; r < 4; ++r) {
                    float sv = sacc[mf][r];
                    if (diag) {
                        int kvg = j * 64 + mf * 16 + 4 * g + r;
                        if (kvg > qg) sv = -1e30f;
                    }
                    p[mf][r] = sv;
                    pmax = fmaxf(pmax, sv);
                }
            pmax = fmaxf(pmax, __shfl_xor(pmax, 16));
            pmax = fmaxf(pmax, __shfl_xor(pmax, 32));
            float pmax_s = pmax * SCL;  // scaled-domain tile max
            if (__any(pmax_s > m_run + 8.f)) {  // T13 defer-max
                float mnew = fmaxf(m_run, pmax_s);
                float corr = exp2a(m_run - mnew);
#pragma unroll
                for (int mf = 0; mf < 4; ++mf)
#pragma unroll
                    for (int r = 0; r < 4; ++r) xacc[mf][r] *= corr;
#pragma unroll
                for (int r = 0; r < 4; ++r) xl[r] *= corr;
                m_run = mnew;
            }
#pragma unroll
            for (int mf = 0; mf < 4; ++mf)
#pragma unroll
                for (int r = 0; r < 4; ++r)
                    p[mf][r] = exp2a(p[mf][r] * SCL - m_run);  // v_fma + v_exp

            // ---- pack P; PV B-frag is lane-local (V columns pre-permuted) ----
            unsigned pkk[4][2];
#pragma unroll
            for (int mf = 0; mf < 4; ++mf) {
                pkk[mf][0] = pk2(p[mf][0], p[mf][1]);
                pkk[mf][1] = pk2(p[mf][2], p[mf][3]);
            }
#pragma unroll
            for (int ks = 0; ks < 2; ++ks) {
                u32x4 tmp = {pkk[2 * ks][0], pkk[2 * ks][1], pkk[2 * ks + 1][0],
                             pkk[2 * ks + 1][1]};
                short8 pb = __builtin_bit_cast(short8, tmp);
                // denominator: l += sum_kv P^T[kv][q] via ones-A MFMA
                xl = __builtin_amdgcn_mfma_f32_16x16x32_bf16(ones, pb, xl, 0, 0, 0);
#pragma unroll
                for (int mf = 0; mf < 4; ++mf) {
                    int row = mf * 16 + q15;
                    unsigned byteoff = ((unsigned)(row * 128 + ks * 64 + g * 16)) ^
                                       ((unsigned)(row & 7) << 4);
                    short8 vf = __builtin_bit_cast(
                        short8, *(const u32x4*)((char*)Vt + byteoff));
                    xacc[mf] = __builtin_amdgcn_mfma_f32_16x16x32_bf16(
                        vf, pb, xacc[mf], 0, 0, 0);
                }
            }
            __syncthreads();
        }

        // ---- epilogue: lane owns q=q15 row; 4x 8B stores ----
        float inv = 1.0f / xl[0];
        size_t rowbase = (size_t)(b * Sn + qblk * 64 + w * 16 + q15) * Dn + h * 64;
#pragma unroll
        for (int mf = 0; mf < 4; ++mf) {
            unsigned w0 = pk2(xacc[mf][0] * inv, xacc[mf][1] * inv);
            unsigned w1 = pk2(xacc[mf][2] * inv, xacc[mf][3] * inv);
            uint2 val = {w0, w1};
            *(uint2*)(Xb + rowbase + mf * 16 + 4 * g) = val;
        }
    }
}

// ---------------------------------------------------------------------------
// Launch. ws layout (bf16): Qb | Kb | Vb | Xb (16 MiB each) | Wb (8 MiB,
// 4 weight matrices bf16, if ws_size permits).
// ---------------------------------------------------------------------------
extern "C" void kernel_launch(void* const* d_in, const int* in_sizes, int n_in,
                              void* d_out, int out_size, void* d_ws, size_t ws_size,
                              hipStream_t stream) {
    (void)in_sizes; (void)n_in; (void)out_size;
    const float* q = (const float*)d_in[0];
    const float* k = (const float*)d_in[1];
    const float* v = (const float*)d_in[2];
    // d_in[3] = mask (causal tril; implemented analytically)
    const float* Wq = (const float*)d_in[4];
    const float* Wk = (const float*)d_in[5];
    const float* Wv = (const float*)d_in[6];
    const float* Wo = (const float*)d_in[7];

    unsigned short* Qb = (unsigned short*)d_ws;
    unsigned short* Kb = Qb + (size_t)Mrows * Dn;
    unsigned short* Vb = Kb + (size_t)Mrows * Dn;
    unsigned short* Xb = Vb + (size_t)Mrows * Dn;
    unsigned short* Wb = Xb + (size_t)Mrows * Dn;

    const size_t needW =
        (size_t)4 * Mrows * Dn * 2 + (size_t)4 * Dn * Dn * 2;  // 64 + 8 MiB
    const bool useWb = ws_size >= needW;

    dim3 blk(256);
    dim3 gblk(512);
    dim3 ggrid(Dn / 128, Mrows / 128);

    if (useWb) {
        cvt_w<<<dim3(Dn * Dn / (256 * 8), 4), blk, 0, stream>>>(Wq, Wk, Wv, Wo, Wb);
        const unsigned short* Wqb = Wb;
        const unsigned short* Wkb = Wb + (size_t)Dn * Dn;
        const unsigned short* Wvb = Wb + (size_t)2 * Dn * Dn;
        const unsigned short* Wob = Wb + (size_t)3 * Dn * Dn;
        gemm_nt<false, true, false><<<ggrid, gblk, 0, stream>>>(q, Wqb, Qb);
        gemm_nt<false, true, false><<<ggrid, gblk, 0, stream>>>(k, Wkb, Kb);
        gemm_nt<false, true, false><<<ggrid, gblk, 0, stream>>>(v, Wvb, Vb);
        attn_fwd<<<dim3(NQB / 2, Bn * Hn), blk, 0, stream>>>(Qb, Kb, Vb, Xb);
        gemm_nt<true, true, true><<<ggrid, gblk, 0, stream>>>(Xb, Wob, d_out);
    } else {
        gemm_nt<false, false, false><<<ggrid, gblk, 0, stream>>>(q, Wq, Qb);
        gemm_nt<false, false, false><<<ggrid, gblk, 0, stream>>>(k, Wk, Kb);
        gemm_nt<false, false, false><<<ggrid, gblk, 0, stream>>>(v, Wv, Vb);
        attn_fwd<<<dim3(NQB / 2, Bn * Hn), blk, 0, stream>>>(Qb, Kb, Vb, Xb);
        gemm_nt<true, false, true><<<ggrid, gblk, 0, stream>>>(Xb, Wo, d_out);
    }
}

// Round 16
// 202.623 us; speedup vs baseline: 1.3699x; 1.0862x over previous
//
#include <hip/hip_runtime.h>
#include <hip/hip_bf16.h>

// Problem constants
constexpr int Bn = 4, Sn = 2048, Dn = 1024, Hn = 16, DKn = 64;
constexpr int Mrows = Bn * Sn;  // 8192
constexpr int NQB = Sn / 64;    // 32 q-chunks of 64 rows

typedef __attribute__((ext_vector_type(8))) short short8;
typedef __attribute__((ext_vector_type(4))) float f32x4;
typedef __attribute__((ext_vector_type(4))) unsigned int u32x4;

#define DEV __device__ __forceinline__

// fp32 -> bf16 RNE, scalar (epilogue scatter only)
DEV unsigned short f2bf(float f) {
    unsigned u = __builtin_bit_cast(unsigned, f);
    u += 0x7FFFu + ((u >> 16) & 1u);
    return (unsigned short)(u >> 16);
}
// fp32 pair -> packed bf16x2 via v_cvt_pk_bf16_f32 (hardware RNE)
DEV unsigned pk2(float a, float b) {
    __hip_bfloat162 h = __float22bfloat162_rn(float2{a, b});
    unsigned u;
    __builtin_memcpy(&u, &h, 4);
    return u;
}
// 2^x via v_exp_f32
DEV float exp2a(float x) {
    float r;
    asm("v_exp_f32 %0, %1" : "=v"(r) : "v"(x));
    return r;
}

// ---------------------------------------------------------------------------
// Weights fp32 -> bf16, one matrix per blockIdx.y. 8 elems/thread.
// ---------------------------------------------------------------------------
__global__ __launch_bounds__(256) void cvt_w(const float* __restrict__ W0,
                                             const float* __restrict__ W1,
                                             const float* __restrict__ W2,
                                             const float* __restrict__ W3,
                                             unsigned short* __restrict__ Out) {
    const float* src = blockIdx.y == 0 ? W0
                     : blockIdx.y == 1 ? W1
                     : blockIdx.y == 2 ? W2 : W3;
    size_t off = ((size_t)blockIdx.x * 256 + threadIdx.x) * 8;
    const float4* s = (const float4*)(src + off);
    float4 a = s[0], b = s[1];
    u32x4 p = {pk2(a.x, a.y), pk2(a.z, a.w), pk2(b.x, b.y), pk2(b.z, b.w)};
    *(u32x4*)(Out + (size_t)blockIdx.y * (Dn * Dn) + off) = p;
}

// ---------------------------------------------------------------------------
// GEMM body: C[m,n] = sum_k A[m,k] * W[n,k]  (y = x @ W^T), M=8192, N=K=1024.
// 128x128 tile, BK=32, 512 threads (8 waves, 2x4 wave grid, 32x64/wave) —
// R15 win: 16 waves/CU at identical tile/traffic.
// XCD-AWARE REMAP (R12 win): all 8 n-blocks of one A-panel share bid%8 ->
// same XCD L2; per-XCD A set = 4MB = L2 size. Bijective.
// Reg-prefetch of next K-step during compute. A/B optionally bf16.
// ---------------------------------------------------------------------------
template <bool ABF16, bool BBF16, bool OUTF32>
DEV void gemm_body(const void* __restrict__ Ap, const void* __restrict__ Bw,
                   void* __restrict__ Out) {
    __shared__ alignas(16) unsigned short As[128 * 40];
    __shared__ alignas(16) unsigned short Bs[128 * 40];

    const int tid = threadIdx.x;  // 0..511
    const int bid = (int)(blockIdx.y * gridDim.x + blockIdx.x);
    const int xcd = bid & 7;
    const int jj = bid >> 3;
    const int m0 = (xcd + ((jj & 7) << 3)) * 128;  // 64 m-panels
    const int n0 = (jj >> 3) * 128;                // 8 n-panels
    const int lane = tid & 63;
    const int w = tid >> 6;                 // 0..7
    const int wm = (w >> 1) * 32;           // 4 m-waves x 32 rows
    const int wn = (w & 1) * 64;            // 2 n-waves x 64 cols
    const int g = lane >> 4, q15 = lane & 15;

    f32x4 acc[2][4] = {};

    const int srow = tid >> 2, sseg = tid & 3;  // 128 rows x 4 segs of 8 elems

    const float* Af = (const float*)Ap;
    const unsigned short* Ab = (const unsigned short*)Ap;
    const float* Bf = (const float*)Bw;
    const unsigned short* Bb = (const unsigned short*)Bw;

    float4 fa0, fa1, fb0, fb1;
    u32x4 ua0, ub0;

    auto loadA = [&](int kk) {
        if constexpr (ABF16) {
            ua0 = *(const u32x4*)(Ab + (size_t)(m0 + srow) * Dn + kk + sseg * 8);
        } else {
            const float4* s =
                (const float4*)(Af + (size_t)(m0 + srow) * Dn + kk + sseg * 8);
            fa0 = s[0];
            fa1 = s[1];
        }
    };
    auto loadB = [&](int kk) {
        if constexpr (BBF16) {
            ub0 = *(const u32x4*)(Bb + (size_t)(n0 + srow) * Dn + kk + sseg * 8);
        } else {
            const float4* s =
                (const float4*)(Bf + (size_t)(n0 + srow) * Dn + kk + sseg * 8);
            fb0 = s[0];
            fb1 = s[1];
        }
    };
    auto store = [&]() {
        u32x4* da = (u32x4*)(&As[srow * 40 + sseg * 8]);
        if constexpr (ABF16) {
            da[0] = ua0;
        } else {
            u32x4 p0 = {pk2(fa0.x, fa0.y), pk2(fa0.z, fa0.w), pk2(fa1.x, fa1.y),
                        pk2(fa1.z, fa1.w)};
            da[0] = p0;
        }
        u32x4* db = (u32x4*)(&Bs[srow * 40 + sseg * 8]);
        if constexpr (BBF16) {
            db[0] = ub0;
        } else {
            u32x4 q0 = {pk2(fb0.x, fb0.y), pk2(fb0.z, fb0.w), pk2(fb1.x, fb1.y),
                        pk2(fb1.z, fb1.w)};
            db[0] = q0;
        }
    };

    loadA(0);
    loadB(0);
    for (int kk = 0; kk < Dn; kk += 32) {
        store();
        __syncthreads();
        if (kk + 32 < Dn) {
            loadA(kk + 32);
            loadB(kk + 32);
        }

        short8 af[2], bf[4];
#pragma unroll
        for (int mf = 0; mf < 2; ++mf)
            af[mf] = __builtin_bit_cast(
                short8, *(const u32x4*)(&As[(wm + mf * 16 + q15) * 40 + g * 8]));
#pragma unroll
        for (int nf = 0; nf < 4; ++nf)
            bf[nf] = __builtin_bit_cast(
                short8, *(const u32x4*)(&Bs[(wn + nf * 16 + q15) * 40 + g * 8]));
#pragma unroll
        for (int mf = 0; mf < 2; ++mf)
#pragma unroll
            for (int nf = 0; nf < 4; ++nf)
                acc[mf][nf] = __builtin_amdgcn_mfma_f32_16x16x32_bf16(
                    af[mf], bf[nf], acc[mf][nf], 0, 0, 0);
        __syncthreads();
    }

#pragma unroll
    for (int mf = 0; mf < 2; ++mf)
#pragma unroll
        for (int nf = 0; nf < 4; ++nf)
#pragma unroll
            for (int r = 0; r < 4; ++r) {
                int m = m0 + wm + mf * 16 + 4 * g + r;
                int n = n0 + wn + nf * 16 + q15;
                float val = acc[mf][nf][r];
                if (OUTF32) {
                    ((float*)Out)[(size_t)m * Dn + n] = val;
                } else {
                    int b = m >> 11, s = m & (Sn - 1);
                    int h = n >> 6, dk = n & 63;
                    ((unsigned short*)Out)[(((size_t)(b * Hn + h) * Sn + s) << 6) +
                                           dk] = f2bf(val);
                }
            }
}

template <bool ABF16, bool BBF16, bool OUTF32>
__global__ __launch_bounds__(512) void gemm_nt(const void* __restrict__ Ap,
                                               const void* __restrict__ Bw,
                                               void* __restrict__ Out) {
    gemm_body<ABF16, BBF16, OUTF32>(Ap, Bw, Out);
}

// ---------------------------------------------------------------------------
// Causal flash attention — 8-WAVE blocks (R16): each staged 64-kv tile now
// feeds 128 q-rows (8 waves x 16) instead of 64. Block-iterations halve
// (512 x 34 vs 1024 x 33) -> half the per-iteration fixed cost (stage +
// 2 barriers + latency, measured ~1500cy/iter of the 2120cy total).
// Pairing {15-p, p} of 128-row chunks -> uniform 34 iters/block.
// Per-wave diagonal: jdiag = 2c + (w>>2); tiles beyond it skipped via
// wave-uniform guard. Single-buffer LDS:
//   Kt: [64kv][64dk] XOR-swizzled (byte ^= (row&7)<<4)
//   Vt: [64dk][64 kv-PERMUTED] (R11 win): col_new(kv) = (kv&32)|((kv&12)
//   <<1)|((kv&16)>>2)|(kv&3) makes the PV B-frag the lane's own pkk regs.
// QK^T swapped; max over RAW scores, SCL folded into exp FMA; T13
// defer-max; T14 reg-prefetch; denominator via ones-A MFMA.
// NOTE: no min-waves in launch_bounds (R7: register cap -> 456MB spill).
// ---------------------------------------------------------------------------
__global__ __launch_bounds__(512) void attn_fwd(
    const unsigned short* __restrict__ Qb, const unsigned short* __restrict__ Kb,
    const unsigned short* __restrict__ Vb, unsigned short* __restrict__ Xb) {
    __shared__ alignas(16) unsigned short Kt[64 * 64];
    __shared__ alignas(16) unsigned short Vt[64 * 64];

    constexpr float SCL = 0.18033688f;  // 0.125 * log2(e)

    const int tid = threadIdx.x;  // 0..511
    const int pair = blockIdx.x;  // 0..7
    const int bh = blockIdx.y;
    const int b = bh >> 4, h = bh & 15;
    const int lane = tid & 63, w = tid >> 6;  // w: 0..7
    const int g = lane >> 4, q15 = lane & 15;

    const unsigned short* Qh = Qb + (size_t)bh * Sn * DKn;
    const unsigned short* Kh = Kb + (size_t)bh * Sn * DKn;
    const unsigned short* Vh = Vb + (size_t)bh * Sn * DKn;

    const int st_row = tid >> 3, st_seg = tid & 7;  // K staging: 1x16B/thread
    const int sv_kv = tid & 63, sv_g = tid >> 6;    // V staging: 8 dk/thread
    const int sel = sv_kv & 1;
    // permuted byte col base in Vt (bit0 of kv preserved by col_new)
    const int kv_even = sv_kv & ~1;
    const unsigned kvp = (unsigned)(((kv_even & 32) | ((kv_even & 12) << 1) |
                                     ((kv_even & 16) >> 2) | (kv_even & 3)) *
                                    2);

    // constant all-ones bf16 A-fragment for the denominator MFMA
    const short8 ones = {0x3F80, 0x3F80, 0x3F80, 0x3F80,
                         0x3F80, 0x3F80, 0x3F80, 0x3F80};

    u32x4 kr0, vr0;  // prefetch registers
    auto load_kv = [&](int j) {
        kr0 = *(const u32x4*)(Kh + (size_t)(j * 64 + st_row) * DKn + st_seg * 8);
        vr0 = *(const u32x4*)(Vh + (size_t)(j * 64 + sv_kv) * DKn + sv_g * 8);
    };

    for (int hp = 0; hp < 2; ++hp) {
        const int c = hp == 0 ? (15 - pair) : pair;  // 128-row chunk index
        const int jmax = 2 * c + 1;
        const int jdiag = 2 * c + (w >> 2);  // this wave's diagonal tile
        const int qg = c * 128 + w * 16 + q15;  // this lane's q row

        short8 qf[2];
#pragma unroll
        for (int ks = 0; ks < 2; ++ks)
            qf[ks] = __builtin_bit_cast(
                short8, *(const u32x4*)(Qh + (size_t)qg * DKn + ks * 32 + g * 8));

        f32x4 xacc[4] = {};  // O^T: xacc[mf][r] = O[q=q15][d=mf*16+4g+r]
        f32x4 xl = {};       // denominator accumulator (all r identical)
        float m_run = -1e30f;  // running max, scaled (log2) domain

        load_kv(0);
        for (int j = 0; j <= jmax; ++j) {
            // ---- write staged KV regs to LDS ----
            {
                unsigned b0 = ((unsigned)(st_row * 128 + st_seg * 16)) ^
                              ((unsigned)(st_row & 7) << 4);
                *(u32x4*)((char*)Kt + b0) = kr0;
            }
            {
                int dk0 = sv_g * 8;
#pragma unroll
                for (int i = 0; i < 4; ++i) {
                    unsigned mine = vr0[i];
                    unsigned theirs = (unsigned)__shfl_xor((int)mine, 1);
                    int dk_abs = dk0 + 2 * i + sel;
                    unsigned out = sel ? ((theirs >> 16) | (mine & 0xffff0000u))
                                       : ((mine & 0xffffu) | (theirs << 16));
                    unsigned byteoff = ((unsigned)(dk_abs * 128) + kvp) ^
                                       ((unsigned)(dk_abs & 7) << 4);
                    *(unsigned*)((char*)Vt + byteoff) = out;
                }
            }
            __syncthreads();

            // next tile's loads in flight under the compute
            if (j < jmax) load_kv(j + 1);

            if (j <= jdiag) {  // wave-uniform guard (past-diag tiles skipped)
                // ---- QK^T (swapped): sacc rows = kv, cols = q ----
                f32x4 sacc[4] = {};
#pragma unroll
                for (int mf = 0; mf < 4; ++mf) {
                    int row = mf * 16 + q15;
#pragma unroll
                    for (int ks = 0; ks < 2; ++ks) {
                        unsigned byteoff =
                            ((unsigned)(row * 128 + ks * 64 + g * 16)) ^
                            ((unsigned)(row & 7) << 4);
                        short8 kf = __builtin_bit_cast(
                            short8, *(const u32x4*)((char*)Kt + byteoff));
                        sacc[mf] = __builtin_amdgcn_mfma_f32_16x16x32_bf16(
                            kf, qf[ks], sacc[mf], 0, 0, 0);
                    }
                }

                // ---- mask + online softmax; raw-score max, SCL via FMA ----
                float p[4][4];
                float pmax = -1e30f;
                const bool diag = (j == jdiag);
#pragma unroll
                for (int mf = 0; mf < 4; ++mf)
#pragma unroll
                    for (int r = 0; r < 4; ++r) {
                        float sv = sacc[mf][r];
                        if (diag) {
                            int kvg = j * 64 + mf * 16 + 4 * g + r;
                            if (kvg > qg) sv = -1e30f;
                        }
                        p[mf][r] = sv;
                        pmax = fmaxf(pmax, sv);
                    }
                pmax = fmaxf(pmax, __shfl_xor(pmax, 16));
                pmax = fmaxf(pmax, __shfl_xor(pmax, 32));
                float pmax_s = pmax * SCL;  // scaled-domain tile max
                if (__any(pmax_s > m_run + 8.f)) {  // T13 defer-max
                    float mnew = fmaxf(m_run, pmax_s);
                    float corr = exp2a(m_run - mnew);
#pragma unroll
                    for (int mf = 0; mf < 4; ++mf)
#pragma unroll
                        for (int r = 0; r < 4; ++r) xacc[mf][r] *= corr;
#pragma unroll
                    for (int r = 0; r < 4; ++r) xl[r] *= corr;
                    m_run = mnew;
                }
#pragma unroll
                for (int mf = 0; mf < 4; ++mf)
#pragma unroll
                    for (int r = 0; r < 4; ++r)
                        p[mf][r] = exp2a(p[mf][r] * SCL - m_run);

                // ---- pack P; PV B-frag lane-local (V cols pre-permuted) ----
                unsigned pkk[4][2];
#pragma unroll
                for (int mf = 0; mf < 4; ++mf) {
                    pkk[mf][0] = pk2(p[mf][0], p[mf][1]);
                    pkk[mf][1] = pk2(p[mf][2], p[mf][3]);
                }
#pragma unroll
                for (int ks = 0; ks < 2; ++ks) {
                    u32x4 tmp = {pkk[2 * ks][0], pkk[2 * ks][1],
                                 pkk[2 * ks + 1][0], pkk[2 * ks + 1][1]};
                    short8 pb = __builtin_bit_cast(short8, tmp);
                    // denominator: l += sum_kv P^T[kv][q] via ones-A MFMA
                    xl = __builtin_amdgcn_mfma_f32_16x16x32_bf16(ones, pb, xl,
                                                                 0, 0, 0);
#pragma unroll
                    for (int mf = 0; mf < 4; ++mf) {
                        int row = mf * 16 + q15;
                        unsigned byteoff =
                            ((unsigned)(row * 128 + ks * 64 + g * 16)) ^
                            ((unsigned)(row & 7) << 4);
                        short8 vf = __builtin_bit_cast(
                            short8, *(const u32x4*)((char*)Vt + byteoff));
                        xacc[mf] = __builtin_amdgcn_mfma_f32_16x16x32_bf16(
                            vf, pb, xacc[mf], 0, 0, 0);
                    }
                }
            }
            __syncthreads();
        }

        // ---- epilogue: lane owns q=q15 row; 4x 8B stores ----
        float inv = 1.0f / xl[0];
        size_t rowbase = (size_t)(b * Sn + c * 128 + w * 16 + q15) * Dn + h * 64;
#pragma unroll
        for (int mf = 0; mf < 4; ++mf) {
            unsigned w0 = pk2(xacc[mf][0] * inv, xacc[mf][1] * inv);
            unsigned w1 = pk2(xacc[mf][2] * inv, xacc[mf][3] * inv);
            uint2 val = {w0, w1};
            *(uint2*)(Xb + rowbase + mf * 16 + 4 * g) = val;
        }
    }
}

// ---------------------------------------------------------------------------
// Launch. ws layout (bf16): Qb | Kb | Vb | Xb (16 MiB each) | Wb (8 MiB,
// 4 weight matrices bf16, if ws_size permits).
// ---------------------------------------------------------------------------
extern "C" void kernel_launch(void* const* d_in, const int* in_sizes, int n_in,
                              void* d_out, int out_size, void* d_ws, size_t ws_size,
                              hipStream_t stream) {
    (void)in_sizes; (void)n_in; (void)out_size;
    const float* q = (const float*)d_in[0];
    const float* k = (const float*)d_in[1];
    const float* v = (const float*)d_in[2];
    // d_in[3] = mask (causal tril; implemented analytically)
    const float* Wq = (const float*)d_in[4];
    const float* Wk = (const float*)d_in[5];
    const float* Wv = (const float*)d_in[6];
    const float* Wo = (const float*)d_in[7];

    unsigned short* Qb = (unsigned short*)d_ws;
    unsigned short* Kb = Qb + (size_t)Mrows * Dn;
    unsigned short* Vb = Kb + (size_t)Mrows * Dn;
    unsigned short* Xb = Vb + (size_t)Mrows * Dn;
    unsigned short* Wb = Xb + (size_t)Mrows * Dn;

    const size_t needW =
        (size_t)4 * Mrows * Dn * 2 + (size_t)4 * Dn * Dn * 2;  // 64 + 8 MiB
    const bool useWb = ws_size >= needW;

    dim3 blk(256);
    dim3 gblk(512);
    dim3 ggrid(Dn / 128, Mrows / 128);
    dim3 agrid(NQB / 4, Bn * Hn);  // 8 pairs of 128-row chunks

    if (useWb) {
        cvt_w<<<dim3(Dn * Dn / (256 * 8), 4), blk, 0, stream>>>(Wq, Wk, Wv, Wo, Wb);
        const unsigned short* Wqb = Wb;
        const unsigned short* Wkb = Wb + (size_t)Dn * Dn;
        const unsigned short* Wvb = Wb + (size_t)2 * Dn * Dn;
        const unsigned short* Wob = Wb + (size_t)3 * Dn * Dn;
        gemm_nt<false, true, false><<<ggrid, gblk, 0, stream>>>(q, Wqb, Qb);
        gemm_nt<false, true, false><<<ggrid, gblk, 0, stream>>>(k, Wkb, Kb);
        gemm_nt<false, true, false><<<ggrid, gblk, 0, stream>>>(v, Wvb, Vb);
        attn_fwd<<<agrid, gblk, 0, stream>>>(Qb, Kb, Vb, Xb);
        gemm_nt<true, true, true><<<ggrid, gblk, 0, stream>>>(Xb, Wob, d_out);
    } else {
        gemm_nt<false, false, false><<<ggrid, gblk, 0, stream>>>(q, Wq, Qb);
        gemm_nt<false, false, false><<<ggrid, gblk, 0, stream>>>(k, Wk, Kb);
        gemm_nt<false, false, false><<<ggrid, gblk, 0, stream>>>(v, Wv, Vb);
        attn_fwd<<<agrid, gblk, 0, stream>>>(Qb, Kb, Vb, Xb);
        gemm_nt<true, false, true><<<ggrid, gblk, 0, stream>>>(Xb, Wo, d_out);
    }
}

// Round 17
// 193.604 us; speedup vs baseline: 1.4337x; 1.0466x over previous
//
#include <hip/hip_runtime.h>
#include <hip/hip_bf16.h>

// Problem constants
constexpr int Bn = 4, Sn = 2048, Dn = 1024, Hn = 16, DKn = 64;
constexpr int Mrows = Bn * Sn;  // 8192
constexpr int NQB = Sn / 64;    // 32 q-chunks of 64 rows

typedef __attribute__((ext_vector_type(8))) short short8;
typedef __attribute__((ext_vector_type(4))) float f32x4;
typedef __attribute__((ext_vector_type(4))) unsigned int u32x4;

#define DEV __device__ __forceinline__

constexpr float QSCL = 0.18033688f;  // 0.125 * log2(e), folded into Q proj

// fp32 -> bf16 RNE, scalar (epilogue scatter only)
DEV unsigned short f2bf(float f) {
    unsigned u = __builtin_bit_cast(unsigned, f);
    u += 0x7FFFu + ((u >> 16) & 1u);
    return (unsigned short)(u >> 16);
}
// fp32 pair -> packed bf16x2 via v_cvt_pk_bf16_f32 (hardware RNE)
DEV unsigned pk2(float a, float b) {
    __hip_bfloat162 h = __float22bfloat162_rn(float2{a, b});
    unsigned u;
    __builtin_memcpy(&u, &h, 4);
    return u;
}
// 2^x via v_exp_f32
DEV float exp2a(float x) {
    float r;
    asm("v_exp_f32 %0, %1" : "=v"(r) : "v"(x));
    return r;
}

// ---------------------------------------------------------------------------
// Weights fp32 -> bf16, one matrix per blockIdx.y. 8 elems/thread.
// ---------------------------------------------------------------------------
__global__ __launch_bounds__(256) void cvt_w(const float* __restrict__ W0,
                                             const float* __restrict__ W1,
                                             const float* __restrict__ W2,
                                             const float* __restrict__ W3,
                                             unsigned short* __restrict__ Out) {
    const float* src = blockIdx.y == 0 ? W0
                     : blockIdx.y == 1 ? W1
                     : blockIdx.y == 2 ? W2 : W3;
    size_t off = ((size_t)blockIdx.x * 256 + threadIdx.x) * 8;
    const float4* s = (const float4*)(src + off);
    float4 a = s[0], b = s[1];
    u32x4 p = {pk2(a.x, a.y), pk2(a.z, a.w), pk2(b.x, b.y), pk2(b.z, b.w)};
    *(u32x4*)(Out + (size_t)blockIdx.y * (Dn * Dn) + off) = p;
}

// ---------------------------------------------------------------------------
// GEMM body: C[m,n] = sum_k A[m,k] * W[n,k]  (y = x @ W^T), M=8192, N=K=1024.
// 128x128 tile, **BK=64** (R16: at BK=32 the 1-deep prefetch issued loads
// ~400cy before use vs ~900cy HBM latency -> every iter stalled at the
// barrier; BK=64 iteration body ~800cy covers the latency and halves the
// barrier count). 512 threads (8 waves, 2x4 wave grid, 32x64/wave).
// LDS rows padded to 72 shorts (144B = 36 dwords -> even bank spread).
// Fragments read per-ks to keep VGPR ~110 (<128 keeps 16 waves/CU).
// XCD-AWARE REMAP (R12 win): all 8 n-blocks of one A-panel share bid%8.
// oscale: multiplied into outputs (Q proj gets 0.125*log2e for attn).
// ---------------------------------------------------------------------------
template <bool ABF16, bool BBF16, bool OUTF32>
DEV void gemm_body(const void* __restrict__ Ap, const void* __restrict__ Bw,
                   void* __restrict__ Out, float oscale) {
    __shared__ alignas(16) unsigned short As[128 * 72];
    __shared__ alignas(16) unsigned short Bs[128 * 72];

    const int tid = threadIdx.x;  // 0..511
    const int bid = (int)(blockIdx.y * gridDim.x + blockIdx.x);
    const int xcd = bid & 7;
    const int jj = bid >> 3;
    const int m0 = (xcd + ((jj & 7) << 3)) * 128;  // 64 m-panels
    const int n0 = (jj >> 3) * 128;                // 8 n-panels
    const int lane = tid & 63;
    const int w = tid >> 6;                 // 0..7
    const int wm = (w >> 1) * 32;           // 4 m-waves x 32 rows
    const int wn = (w & 1) * 64;            // 2 n-waves x 64 cols
    const int g = lane >> 4, q15 = lane & 15;

    f32x4 acc[2][4] = {};

    const int srow = tid >> 2, sseg = tid & 3;  // 128 rows x 4 segs of 16 elems

    const float* Af = (const float*)Ap;
    const unsigned short* Ab = (const unsigned short*)Ap;
    const float* Bf = (const float*)Bw;
    const unsigned short* Bb = (const unsigned short*)Bw;

    float4 fa[4], fb[4];
    u32x4 ua[2], ub[2];

    auto loadA = [&](int kk) {
        if constexpr (ABF16) {
            const u32x4* s =
                (const u32x4*)(Ab + (size_t)(m0 + srow) * Dn + kk + sseg * 16);
            ua[0] = s[0];
            ua[1] = s[1];
        } else {
            const float4* s =
                (const float4*)(Af + (size_t)(m0 + srow) * Dn + kk + sseg * 16);
            fa[0] = s[0]; fa[1] = s[1]; fa[2] = s[2]; fa[3] = s[3];
        }
    };
    auto loadB = [&](int kk) {
        if constexpr (BBF16) {
            const u32x4* s =
                (const u32x4*)(Bb + (size_t)(n0 + srow) * Dn + kk + sseg * 16);
            ub[0] = s[0];
            ub[1] = s[1];
        } else {
            const float4* s =
                (const float4*)(Bf + (size_t)(n0 + srow) * Dn + kk + sseg * 16);
            fb[0] = s[0]; fb[1] = s[1]; fb[2] = s[2]; fb[3] = s[3];
        }
    };
    auto store = [&]() {
        u32x4* da = (u32x4*)(&As[srow * 72 + sseg * 16]);
        if constexpr (ABF16) {
            da[0] = ua[0];
            da[1] = ua[1];
        } else {
            u32x4 p0 = {pk2(fa[0].x, fa[0].y), pk2(fa[0].z, fa[0].w),
                        pk2(fa[1].x, fa[1].y), pk2(fa[1].z, fa[1].w)};
            u32x4 p1 = {pk2(fa[2].x, fa[2].y), pk2(fa[2].z, fa[2].w),
                        pk2(fa[3].x, fa[3].y), pk2(fa[3].z, fa[3].w)};
            da[0] = p0;
            da[1] = p1;
        }
        u32x4* db = (u32x4*)(&Bs[srow * 72 + sseg * 16]);
        if constexpr (BBF16) {
            db[0] = ub[0];
            db[1] = ub[1];
        } else {
            u32x4 q0 = {pk2(fb[0].x, fb[0].y), pk2(fb[0].z, fb[0].w),
                        pk2(fb[1].x, fb[1].y), pk2(fb[1].z, fb[1].w)};
            u32x4 q1 = {pk2(fb[2].x, fb[2].y), pk2(fb[2].z, fb[2].w),
                        pk2(fb[3].x, fb[3].y), pk2(fb[3].z, fb[3].w)};
            db[0] = q0;
            db[1] = q1;
        }
    };

    loadA(0);
    loadB(0);
    for (int kk = 0; kk < Dn; kk += 64) {
        store();
        __syncthreads();
        if (kk + 64 < Dn) {
            loadA(kk + 64);
            loadB(kk + 64);
        }

#pragma unroll
        for (int ks = 0; ks < 2; ++ks) {
            short8 af[2], bf4[4];
#pragma unroll
            for (int mf = 0; mf < 2; ++mf)
                af[mf] = __builtin_bit_cast(
                    short8, *(const u32x4*)(&As[(wm + mf * 16 + q15) * 72 +
                                                ks * 32 + g * 8]));
#pragma unroll
            for (int nf = 0; nf < 4; ++nf)
                bf4[nf] = __builtin_bit_cast(
                    short8, *(const u32x4*)(&Bs[(wn + nf * 16 + q15) * 72 +
                                                ks * 32 + g * 8]));
#pragma unroll
            for (int mf = 0; mf < 2; ++mf)
#pragma unroll
                for (int nf = 0; nf < 4; ++nf)
                    acc[mf][nf] = __builtin_amdgcn_mfma_f32_16x16x32_bf16(
                        af[mf], bf4[nf], acc[mf][nf], 0, 0, 0);
        }
        __syncthreads();
    }

#pragma unroll
    for (int mf = 0; mf < 2; ++mf)
#pragma unroll
        for (int nf = 0; nf < 4; ++nf)
#pragma unroll
            for (int r = 0; r < 4; ++r) {
                int m = m0 + wm + mf * 16 + 4 * g + r;
                int n = n0 + wn + nf * 16 + q15;
                float val = acc[mf][nf][r] * oscale;
                if (OUTF32) {
                    ((float*)Out)[(size_t)m * Dn + n] = val;
                } else {
                    int b = m >> 11, s = m & (Sn - 1);
                    int h = n >> 6, dk = n & 63;
                    ((unsigned short*)Out)[(((size_t)(b * Hn + h) * Sn + s) << 6) +
                                           dk] = f2bf(val);
                }
            }
}

template <bool ABF16, bool BBF16, bool OUTF32>
__global__ __launch_bounds__(512) void gemm_nt(const void* __restrict__ Ap,
                                               const void* __restrict__ Bw,
                                               void* __restrict__ Out,
                                               float oscale) {
    gemm_body<ABF16, BBF16, OUTF32>(Ap, Bw, Out, oscale);
}

// ---------------------------------------------------------------------------
// Causal flash attention — 8-WAVE blocks (R16 win: 117 -> 87us). Each
// staged 64-kv tile feeds 128 q-rows (8 waves x 16). Pairing {15-p, p} of
// 128-row chunks -> uniform 34 iters/block. Per-wave diagonal jdiag =
// 2c + (w>>2); past-diagonal tiles skipped via wave-uniform guard.
// Q arrives PRE-SCALED by 0.125*log2e (folded into Q-proj epilogue, R17)
// -> scores are already log2-domain; no per-element FMA in softmax.
// Single-buffer LDS:
//   Kt: [64kv][64dk] XOR-swizzled (byte ^= (row&7)<<4)
//   Vt: [64dk][64 kv-PERMUTED] (R11 win): col_new(kv) = (kv&32)|((kv&12)
//   <<1)|((kv&16)>>2)|(kv&3) makes the PV B-frag the lane's own pkk regs.
// QK^T swapped; T13 defer-max; T14 reg-prefetch; denominator via ones-A
// MFMA. NOTE: no min-waves in launch_bounds (R7: cap -> 456MB spill).
// ---------------------------------------------------------------------------
__global__ __launch_bounds__(512) void attn_fwd(
    const unsigned short* __restrict__ Qb, const unsigned short* __restrict__ Kb,
    const unsigned short* __restrict__ Vb, unsigned short* __restrict__ Xb) {
    __shared__ alignas(16) unsigned short Kt[64 * 64];
    __shared__ alignas(16) unsigned short Vt[64 * 64];

    const int tid = threadIdx.x;  // 0..511
    const int pair = blockIdx.x;  // 0..7
    const int bh = blockIdx.y;
    const int b = bh >> 4, h = bh & 15;
    const int lane = tid & 63, w = tid >> 6;  // w: 0..7
    const int g = lane >> 4, q15 = lane & 15;

    const unsigned short* Qh = Qb + (size_t)bh * Sn * DKn;
    const unsigned short* Kh = Kb + (size_t)bh * Sn * DKn;
    const unsigned short* Vh = Vb + (size_t)bh * Sn * DKn;

    const int st_row = tid >> 3, st_seg = tid & 7;  // K staging: 1x16B/thread
    const int sv_kv = tid & 63, sv_g = tid >> 6;    // V staging: 8 dk/thread
    const int sel = sv_kv & 1;
    // permuted byte col base in Vt (bit0 of kv preserved by col_new)
    const int kv_even = sv_kv & ~1;
    const unsigned kvp = (unsigned)(((kv_even & 32) | ((kv_even & 12) << 1) |
                                     ((kv_even & 16) >> 2) | (kv_even & 3)) *
                                    2);

    // constant all-ones bf16 A-fragment for the denominator MFMA
    const short8 ones = {0x3F80, 0x3F80, 0x3F80, 0x3F80,
                         0x3F80, 0x3F80, 0x3F80, 0x3F80};

    u32x4 kr0, vr0;  // prefetch registers
    auto load_kv = [&](int j) {
        kr0 = *(const u32x4*)(Kh + (size_t)(j * 64 + st_row) * DKn + st_seg * 8);
        vr0 = *(const u32x4*)(Vh + (size_t)(j * 64 + sv_kv) * DKn + sv_g * 8);
    };

    for (int hp = 0; hp < 2; ++hp) {
        const int c = hp == 0 ? (15 - pair) : pair;  // 128-row chunk index
        const int jmax = 2 * c + 1;
        const int jdiag = 2 * c + (w >> 2);  // this wave's diagonal tile
        const int qg = c * 128 + w * 16 + q15;  // this lane's q row

        short8 qf[2];
#pragma unroll
        for (int ks = 0; ks < 2; ++ks)
            qf[ks] = __builtin_bit_cast(
                short8, *(const u32x4*)(Qh + (size_t)qg * DKn + ks * 32 + g * 8));

        f32x4 xacc[4] = {};  // O^T: xacc[mf][r] = O[q=q15][d=mf*16+4g+r]
        f32x4 xl = {};       // denominator accumulator (all r identical)
        float m_run = -1e30f;  // running max (log2 domain, Q pre-scaled)

        load_kv(0);
        for (int j = 0; j <= jmax; ++j) {
            // ---- write staged KV regs to LDS ----
            {
                unsigned b0 = ((unsigned)(st_row * 128 + st_seg * 16)) ^
                              ((unsigned)(st_row & 7) << 4);
                *(u32x4*)((char*)Kt + b0) = kr0;
            }
            {
                int dk0 = sv_g * 8;
#pragma unroll
                for (int i = 0; i < 4; ++i) {
                    unsigned mine = vr0[i];
                    unsigned theirs = (unsigned)__shfl_xor((int)mine, 1);
                    int dk_abs = dk0 + 2 * i + sel;
                    unsigned out = sel ? ((theirs >> 16) | (mine & 0xffff0000u))
                                       : ((mine & 0xffffu) | (theirs << 16));
                    unsigned byteoff = ((unsigned)(dk_abs * 128) + kvp) ^
                                       ((unsigned)(dk_abs & 7) << 4);
                    *(unsigned*)((char*)Vt + byteoff) = out;
                }
            }
            __syncthreads();

            // next tile's loads in flight under the compute
            if (j < jmax) load_kv(j + 1);

            if (j <= jdiag) {  // wave-uniform guard (past-diag tiles skipped)
                // ---- QK^T (swapped): sacc rows = kv, cols = q ----
                f32x4 sacc[4] = {};
#pragma unroll
                for (int mf = 0; mf < 4; ++mf) {
                    int row = mf * 16 + q15;
#pragma unroll
                    for (int ks = 0; ks < 2; ++ks) {
                        unsigned byteoff =
                            ((unsigned)(row * 128 + ks * 64 + g * 16)) ^
                            ((unsigned)(row & 7) << 4);
                        short8 kf = __builtin_bit_cast(
                            short8, *(const u32x4*)((char*)Kt + byteoff));
                        sacc[mf] = __builtin_amdgcn_mfma_f32_16x16x32_bf16(
                            kf, qf[ks], sacc[mf], 0, 0, 0);
                    }
                }

                // ---- mask + online softmax (scores already log2-domain) ----
                float p[4][4];
                float pmax = -1e30f;
                const bool diag = (j == jdiag);
#pragma unroll
                for (int mf = 0; mf < 4; ++mf)
#pragma unroll
                    for (int r = 0; r < 4; ++r) {
                        float sv = sacc[mf][r];
                        if (diag) {
                            int kvg = j * 64 + mf * 16 + 4 * g + r;
                            if (kvg > qg) sv = -1e30f;
                        }
                        p[mf][r] = sv;
                        pmax = fmaxf(pmax, sv);
                    }
                pmax = fmaxf(pmax, __shfl_xor(pmax, 16));
                pmax = fmaxf(pmax, __shfl_xor(pmax, 32));
                if (__any(pmax > m_run + 8.f)) {  // T13 defer-max
                    float mnew = fmaxf(m_run, pmax);
                    float corr = exp2a(m_run - mnew);
#pragma unroll
                    for (int mf = 0; mf < 4; ++mf)
#pragma unroll
                        for (int r = 0; r < 4; ++r) xacc[mf][r] *= corr;
#pragma unroll
                    for (int r = 0; r < 4; ++r) xl[r] *= corr;
                    m_run = mnew;
                }
#pragma unroll
                for (int mf = 0; mf < 4; ++mf)
#pragma unroll
                    for (int r = 0; r < 4; ++r)
                        p[mf][r] = exp2a(p[mf][r] - m_run);

                // ---- pack P; PV B-frag lane-local (V cols pre-permuted) ----
                unsigned pkk[4][2];
#pragma unroll
                for (int mf = 0; mf < 4; ++mf) {
                    pkk[mf][0] = pk2(p[mf][0], p[mf][1]);
                    pkk[mf][1] = pk2(p[mf][2], p[mf][3]);
                }
#pragma unroll
                for (int ks = 0; ks < 2; ++ks) {
                    u32x4 tmp = {pkk[2 * ks][0], pkk[2 * ks][1],
                                 pkk[2 * ks + 1][0], pkk[2 * ks + 1][1]};
                    short8 pb = __builtin_bit_cast(short8, tmp);
                    // denominator: l += sum_kv P^T[kv][q] via ones-A MFMA
                    xl = __builtin_amdgcn_mfma_f32_16x16x32_bf16(ones, pb, xl,
                                                                 0, 0, 0);
#pragma unroll
                    for (int mf = 0; mf < 4; ++mf) {
                        int row = mf * 16 + q15;
                        unsigned byteoff =
                            ((unsigned)(row * 128 + ks * 64 + g * 16)) ^
                            ((unsigned)(row & 7) << 4);
                        short8 vf = __builtin_bit_cast(
                            short8, *(const u32x4*)((char*)Vt + byteoff));
                        xacc[mf] = __builtin_amdgcn_mfma_f32_16x16x32_bf16(
                            vf, pb, xacc[mf], 0, 0, 0);
                    }
                }
            }
            __syncthreads();
        }

        // ---- epilogue: lane owns q=q15 row; 4x 8B stores ----
        float inv = 1.0f / xl[0];
        size_t rowbase = (size_t)(b * Sn + c * 128 + w * 16 + q15) * Dn + h * 64;
#pragma unroll
        for (int mf = 0; mf < 4; ++mf) {
            unsigned w0 = pk2(xacc[mf][0] * inv, xacc[mf][1] * inv);
            unsigned w1 = pk2(xacc[mf][2] * inv, xacc[mf][3] * inv);
            uint2 val = {w0, w1};
            *(uint2*)(Xb + rowbase + mf * 16 + 4 * g) = val;
        }
    }
}

// ---------------------------------------------------------------------------
// Launch. ws layout (bf16): Qb | Kb | Vb | Xb (16 MiB each) | Wb (8 MiB,
// 4 weight matrices bf16, if ws_size permits).
// ---------------------------------------------------------------------------
extern "C" void kernel_launch(void* const* d_in, const int* in_sizes, int n_in,
                              void* d_out, int out_size, void* d_ws, size_t ws_size,
                              hipStream_t stream) {
    (void)in_sizes; (void)n_in; (void)out_size;
    const float* q = (const float*)d_in[0];
    const float* k = (const float*)d_in[1];
    const float* v = (const float*)d_in[2];
    // d_in[3] = mask (causal tril; implemented analytically)
    const float* Wq = (const float*)d_in[4];
    const float* Wk = (const float*)d_in[5];
    const float* Wv = (const float*)d_in[6];
    const float* Wo = (const float*)d_in[7];

    unsigned short* Qb = (unsigned short*)d_ws;
    unsigned short* Kb = Qb + (size_t)Mrows * Dn;
    unsigned short* Vb = Kb + (size_t)Mrows * Dn;
    unsigned short* Xb = Vb + (size_t)Mrows * Dn;
    unsigned short* Wb = Xb + (size_t)Mrows * Dn;

    const size_t needW =
        (size_t)4 * Mrows * Dn * 2 + (size_t)4 * Dn * Dn * 2;  // 64 + 8 MiB
    const bool useWb = ws_size >= needW;

    dim3 blk(256);
    dim3 gblk(512);
    dim3 ggrid(Dn / 128, Mrows / 128);
    dim3 agrid(NQB / 4, Bn * Hn);  // 8 pairs of 128-row chunks

    if (useWb) {
        cvt_w<<<dim3(Dn * Dn / (256 * 8), 4), blk, 0, stream>>>(Wq, Wk, Wv, Wo, Wb);
        const unsigned short* Wqb = Wb;
        const unsigned short* Wkb = Wb + (size_t)Dn * Dn;
        const unsigned short* Wvb = Wb + (size_t)2 * Dn * Dn;
        const unsigned short* Wob = Wb + (size_t)3 * Dn * Dn;
        gemm_nt<false, true, false><<<ggrid, gblk, 0, stream>>>(q, Wqb, Qb, QSCL);
        gemm_nt<false, true, false><<<ggrid, gblk, 0, stream>>>(k, Wkb, Kb, 1.0f);
        gemm_nt<false, true, false><<<ggrid, gblk, 0, stream>>>(v, Wvb, Vb, 1.0f);
        attn_fwd<<<agrid, gblk, 0, stream>>>(Qb, Kb, Vb, Xb);
        gemm_nt<true, true, true><<<ggrid, gblk, 0, stream>>>(Xb, Wob, d_out, 1.0f);
    } else {
        gemm_nt<false, false, false><<<ggrid, gblk, 0, stream>>>(q, Wq, Qb, QSCL);
        gemm_nt<false, false, false><<<ggrid, gblk, 0, stream>>>(k, Wk, Kb, 1.0f);
        gemm_nt<false, false, false><<<ggrid, gblk, 0, stream>>>(v, Wv, Vb, 1.0f);
        attn_fwd<<<agrid, gblk, 0, stream>>>(Qb, Kb, Vb, Xb);
        gemm_nt<true, false, true><<<ggrid, gblk, 0, stream>>>(Xb, Wo, d_out, 1.0f);
    }
}